// Round 2
// baseline (378.296 us; speedup 1.0000x reference)
//
#include <hip/hip_runtime.h>
#include <math.h>

// Outputs are a pure function of obs's class (NC=1000 distinct values):
// compute per-class tables once (fp64 trunk for argmin robustness), then
// scatter per batch element. Memory floor = the 134 MB of mandatory writes.
//
// R5: per_class was latency-bound (1000 blocks x 2 waves, ~12 barrier-
// separated phases each waiting on L2 loads). Split every dot-product's
// K-dim across 2x threads (256-thread blocks, h=tid>>7 owns half of K,
// LDS partial combine): halves per-phase chain length, doubles waves/CU.
// VQ per-code fp64 chains unchanged (bit-identical distances + ascending-k
// strict-< tie-break => same idx). Scatter: one thread emits both am and
// sd float4 from a single obs read.

typedef float f4 __attribute__((ext_vector_type(4)));

__device__ __forceinline__ float sigmoidf_(float x){ return 1.0f/(1.0f + expf(-x)); }

// cbT[j*VQN + k] = (double)cb[k*64 + j]  — 256 KB once per launch.
__global__ __launch_bounds__(256) void transpose_cb_kernel(
    const float* __restrict__ cb, double* __restrict__ cbT, int VQN)
{
    int gid = blockIdx.x * 256 + threadIdx.x;
    int total = 64 * VQN;
    if (gid < total) {
        int j = gid / VQN;
        int k = gid - j * VQN;
        cbT[gid] = (double)cb[(size_t)k * 64 + j];
    }
}

__global__ __launch_bounds__(256) void per_class_kernel(
    const float* __restrict__ embed,
    const float* __restrict__ W1, const float* __restrict__ b1,
    const float* __restrict__ W2, const float* __restrict__ b2,
    const float* __restrict__ W3, const float* __restrict__ b3,
    const float* __restrict__ Wp, const float* __restrict__ bp,
    const float* __restrict__ cb, const double* __restrict__ cbT,
    const float* __restrict__ Wa, const float* __restrict__ ba,
    const float* __restrict__ Ws, const float* __restrict__ bs,
    const float* __restrict__ Wc1, const float* __restrict__ bc1,
    const float* __restrict__ Wc2, const float* __restrict__ bc2,
    const float* __restrict__ Wc3, const float* __restrict__ bc3,
    const float* __restrict__ Wc4, const float* __restrict__ bc4,
    float* __restrict__ am_t, float* __restrict__ sd_t,
    float* __restrict__ cr_t, int* __restrict__ idx_t, float* __restrict__ e_t,
    float* __restrict__ loss_slot, int VQN)
{
    const int c   = blockIdx.x;
    const int tid = threadIdx.x;     // 0..255
    const int t   = tid & 127;       // output index
    const int h   = tid >> 7;        // K-half: 0 or 1
    const int i0  = h * 64;
    if (c == 0 && tid == 0) *loss_slot = 0.0f;   // d_out is poisoned each call

    __shared__ double Abuf[128];
    __shared__ double Bbuf[128];
    __shared__ double part[2][128];
    __shared__ double zp[64];
    __shared__ float  qv[64];
    __shared__ double rd[256];
    __shared__ int    ri[256];
    __shared__ float  fpart[2][128];
    __shared__ float  gpart[2][128];
    __shared__ float  hpart[2][128];
    __shared__ float  h1[128], h2[128], h3[32];

    // y = embed[c]
    if (h == 0) Abuf[t] = (double)embed[(size_t)c * 128 + t];
    __syncthreads();

    // z1 = relu(y @ W1 + b1) — each K-half uses 4 independent fp64 chains
    {
        double a0 = (h == 0) ? (double)b1[t] : 0.0, a1 = 0.0, a2 = 0.0, a3 = 0.0;
        for (int i = i0; i < i0 + 64; i += 4) {
            a0 = fma(Abuf[i+0], (double)W1[(i+0) * 128 + t], a0);
            a1 = fma(Abuf[i+1], (double)W1[(i+1) * 128 + t], a1);
            a2 = fma(Abuf[i+2], (double)W1[(i+2) * 128 + t], a2);
            a3 = fma(Abuf[i+3], (double)W1[(i+3) * 128 + t], a3);
        }
        part[h][t] = (a0 + a1) + (a2 + a3);
    }
    __syncthreads();
    if (h == 0) { double acc = part[0][t] + part[1][t]; Bbuf[t] = acc > 0.0 ? acc : 0.0; }
    __syncthreads();

    // z2 = relu(z1 @ W2 + b2)
    {
        double a0 = (h == 0) ? (double)b2[t] : 0.0, a1 = 0.0, a2 = 0.0, a3 = 0.0;
        for (int i = i0; i < i0 + 64; i += 4) {
            a0 = fma(Bbuf[i+0], (double)W2[(i+0) * 128 + t], a0);
            a1 = fma(Bbuf[i+1], (double)W2[(i+1) * 128 + t], a1);
            a2 = fma(Bbuf[i+2], (double)W2[(i+2) * 128 + t], a2);
            a3 = fma(Bbuf[i+3], (double)W2[(i+3) * 128 + t], a3);
        }
        part[h][t] = (a0 + a1) + (a2 + a3);
    }
    __syncthreads();
    if (h == 0) { double acc = part[0][t] + part[1][t]; Abuf[t] = acc > 0.0 ? acc : 0.0; }
    __syncthreads();

    // z3 = relu(z2 @ W3 + b3)
    {
        double a0 = (h == 0) ? (double)b3[t] : 0.0, a1 = 0.0, a2 = 0.0, a3 = 0.0;
        for (int i = i0; i < i0 + 64; i += 4) {
            a0 = fma(Abuf[i+0], (double)W3[(i+0) * 128 + t], a0);
            a1 = fma(Abuf[i+1], (double)W3[(i+1) * 128 + t], a1);
            a2 = fma(Abuf[i+2], (double)W3[(i+2) * 128 + t], a2);
            a3 = fma(Abuf[i+3], (double)W3[(i+3) * 128 + t], a3);
        }
        part[h][t] = (a0 + a1) + (a2 + a3);
    }
    __syncthreads();
    if (h == 0) { double acc = part[0][t] + part[1][t]; Bbuf[t] = acc > 0.0 ? acc : 0.0; }
    __syncthreads();

    // zp = z3 @ Wp + bp   (64 outputs)
    if (t < 64) {
        double a0 = (h == 0) ? (double)bp[t] : 0.0, a1 = 0.0, a2 = 0.0, a3 = 0.0;
        for (int i = i0; i < i0 + 64; i += 4) {
            a0 = fma(Bbuf[i+0], (double)Wp[(i+0) * 64 + t], a0);
            a1 = fma(Bbuf[i+1], (double)Wp[(i+1) * 64 + t], a1);
            a2 = fma(Bbuf[i+2], (double)Wp[(i+2) * 64 + t], a2);
            a3 = fma(Bbuf[i+3], (double)Wp[(i+3) * 64 + t], a3);
        }
        part[h][t] = (a0 + a1) + (a2 + a3);
    }
    __syncthreads();
    if (h == 0 && t < 64) zp[t] = part[0][t] + part[1][t];
    __syncthreads();

    // VQ argmin: 256 threads, 2 codes each (k = tid, tid+256), coalesced
    // via transposed fp64 codebook. Per-code even/odd chains are bit-
    // identical to R4; strict-< first-min ascending + min-idx tie reduce.
    double best = 1e300; int bidx = 0;
    if (VQN == 512) {
        const double* base = cbT + tid;
        double a0e = 0.0, a0o = 0.0, a1e = 0.0, a1o = 0.0;
        for (int j = 0; j < 64; j += 2) {
            const double* r0 = base + (size_t)j * 512;
            const double* r1 = r0 + 512;
            double z0 = zp[j], z1 = zp[j+1];
            double d;
            d = z0 - r0[0];    a0e = fma(d, d, a0e);
            d = z1 - r1[0];    a0o = fma(d, d, a0o);
            d = z0 - r0[256];  a1e = fma(d, d, a1e);
            d = z1 - r1[256];  a1o = fma(d, d, a1o);
        }
        double s0 = a0e + a0o, s1 = a1e + a1o;
        best = s0; bidx = tid;
        if (s1 < best) { best = s1; bidx = tid + 256; }
    } else {
        for (int k = tid; k < VQN; k += 256) {
            const float* crow = cb + (size_t)k * 64;
            double s0 = 0.0, s1 = 0.0;
            for (int j = 0; j < 64; j += 2) {
                double d0 = zp[j+0] - (double)crow[j+0];
                double d1 = zp[j+1] - (double)crow[j+1];
                s0 = fma(d0, d0, s0);
                s1 = fma(d1, d1, s1);
            }
            double s = s0 + s1;
            if (s < best) { best = s; bidx = k; }
        }
    }
    rd[tid] = best; ri[tid] = bidx;
    __syncthreads();
    for (int sft = 128; sft > 0; sft >>= 1) {
        if (tid < sft) {
            if (rd[tid + sft] < rd[tid] || (rd[tid + sft] == rd[tid] && ri[tid + sft] < ri[tid])) {
                rd[tid] = rd[tid + sft]; ri[tid] = ri[tid + sft];
            }
        }
        __syncthreads();
    }
    const int widx = ri[0];
    if (tid < 64) qv[tid] = cb[(size_t)widx * 64 + tid];
    __syncthreads();

    // heads (fp32; q = exact codebook row). K split across h: j in [h*32, h*32+32)
    {
        const int j0 = h * 32;
        float la0 = (h == 0) ? ba[t]  : 0.0f, la1 = 0.0f;
        float ls0 = (h == 0) ? bs[t]  : 0.0f, ls1 = 0.0f;
        float l10 = (h == 0) ? bc1[t] : 0.0f, l11 = 0.0f;
        for (int j = j0; j < j0 + 32; j += 2) {
            float q0 = qv[j], q1 = qv[j+1];
            la0 = fmaf(q0, Wa[j * 128 + t], la0);
            la1 = fmaf(q1, Wa[(j+1) * 128 + t], la1);
            ls0 = fmaf(q0, Ws[j * 128 + t], ls0);
            ls1 = fmaf(q1, Ws[(j+1) * 128 + t], ls1);
            l10 = fmaf(q0, Wc1[j * 128 + t], l10);
            l11 = fmaf(q1, Wc1[(j+1) * 128 + t], l11);
        }
        fpart[h][t] = la0 + la1;
        gpart[h][t] = ls0 + ls1;
        hpart[h][t] = l10 + l11;
    }
    __syncthreads();
    if (h == 0) {
        am_t[(size_t)c * 128 + t] = sigmoidf_(fpart[0][t] + fpart[1][t]);
        sd_t[(size_t)c * 128 + t] = sigmoidf_(gpart[0][t] + gpart[1][t]) * 1.0f + 1e-8f; // SQUISH=1.0
        h1[t] = sigmoidf_(hpart[0][t] + hpart[1][t]);
    }
    __syncthreads();

    // critic layer 2 (128->128), K split across h
    {
        float l0 = (h == 0) ? bc2[t] : 0.0f, l1 = 0.0f;
        for (int i = i0; i < i0 + 64; i += 2) {
            l0 = fmaf(h1[i],   Wc2[i * 128 + t],     l0);
            l1 = fmaf(h1[i+1], Wc2[(i+1) * 128 + t], l1);
        }
        fpart[h][t] = l0 + l1;
    }
    __syncthreads();
    if (h == 0) h2[t] = sigmoidf_(fpart[0][t] + fpart[1][t]);
    __syncthreads();

    // critic layer 3 (128->32), K split across h
    if (t < 32) {
        float l0 = (h == 0) ? bc3[t] : 0.0f, l1 = 0.0f;
        for (int i = i0; i < i0 + 64; i += 2) {
            l0 = fmaf(h2[i],   Wc3[i * 32 + t],     l0);
            l1 = fmaf(h2[i+1], Wc3[(i+1) * 32 + t], l1);
        }
        fpart[h][t] = l0 + l1;
    }
    __syncthreads();
    if (h == 0 && t < 32) h3[t] = sigmoidf_(fpart[0][t] + fpart[1][t]);
    __syncthreads();

    if (tid == 0) {
        float l4 = bc4[0];
        for (int i = 0; i < 32; ++i) l4 = fmaf(h3[i], Wc4[i], l4);
        cr_t[c] = l4;              // no sigmoid on final critic layer
        idx_t[c] = widx;
        double e0 = 0.0, e1 = 0.0;
        for (int j = 0; j < 64; j += 2) {
            double d0 = (double)qv[j]   - zp[j];
            double d1 = (double)qv[j+1] - zp[j+1];
            e0 = fma(d0, d0, e0); e1 = fma(d1, d1, e1);
        }
        e_t[c] = (float)(e0 + e1); // sum over 64 dims of (quant-z)^2
    }
}

// Merged scatter: blocks [0, vecBlocks) emit BOTH am and sd float4 per
// thread from one obs read (coalesced nontemporal); trailing blocks do
// the critic/idx scatter and vq_loss reduction (one atomic per block).
__global__ __launch_bounds__(256) void scatter_kernel(
    const int* __restrict__ obs,
    const f4* __restrict__ am_t, const f4* __restrict__ sd_t,
    const float* __restrict__ cr_t, const int* __restrict__ idx_t,
    const float* __restrict__ e_t,
    f4* __restrict__ out_vec, float* __restrict__ out_critic,
    float* __restrict__ out_idx, float* __restrict__ out_loss,
    int B, float scale)
{
    __shared__ float red[256];
    const int vecBlocks = (B * 32) / 256;           // B*128/4 f4-slots per half
    if ((int)blockIdx.x < vecBlocks) {
        int gid = blockIdx.x * 256 + threadIdx.x;
        int b = gid >> 5;                           // 32 float4 per row
        int j = gid & 31;
        size_t row = (size_t)obs[b] * 32 + j;
        __builtin_nontemporal_store(am_t[row], &out_vec[gid]);
        __builtin_nontemporal_store(sd_t[row], &out_vec[(size_t)B * 32 + gid]);
        return;
    }
    int b = (blockIdx.x - vecBlocks) * 256 + threadIdx.x;
    float e = 0.0f;
    if (b < B) {
        int o = obs[b];
        __builtin_nontemporal_store(cr_t[o], &out_critic[b]);
        __builtin_nontemporal_store((float)idx_t[o], &out_idx[b]);
        e = e_t[o];
    }
    red[threadIdx.x] = e;
    __syncthreads();
    for (int s = 128; s > 0; s >>= 1) {
        if (threadIdx.x < s) red[threadIdx.x] += red[threadIdx.x + s];
        __syncthreads();
    }
    if (threadIdx.x == 0) atomicAdd(out_loss, red[0] * scale);
}

extern "C" void kernel_launch(void* const* d_in, const int* in_sizes, int n_in,
                              void* d_out, int out_size, void* d_ws, size_t ws_size,
                              hipStream_t stream)
{
    const int*   obs   = (const int*)  d_in[0];
    const float* embed = (const float*)d_in[1];
    const float* W1    = (const float*)d_in[2];
    const float* b1    = (const float*)d_in[3];
    const float* W2    = (const float*)d_in[4];
    const float* b2    = (const float*)d_in[5];
    const float* W3    = (const float*)d_in[6];
    const float* b3    = (const float*)d_in[7];
    const float* Wp    = (const float*)d_in[8];
    const float* bp    = (const float*)d_in[9];
    const float* cb    = (const float*)d_in[10];
    const float* Wa    = (const float*)d_in[11];
    const float* ba    = (const float*)d_in[12];
    const float* Ws    = (const float*)d_in[13];
    const float* bs    = (const float*)d_in[14];
    const float* Wc1   = (const float*)d_in[15];
    const float* bc1   = (const float*)d_in[16];
    const float* Wc2   = (const float*)d_in[17];
    const float* bc2   = (const float*)d_in[18];
    const float* Wc3   = (const float*)d_in[19];
    const float* bc3   = (const float*)d_in[20];
    const float* Wc4   = (const float*)d_in[21];
    const float* bc4   = (const float*)d_in[22];

    const int B   = in_sizes[0];
    const int NC  = in_sizes[1] / 128;
    const int VQN = in_sizes[10] / 64;

    // workspace: cbT (fp64, 8-byte aligned at ws base) then float tables
    double* cbT  = (double*)d_ws;                       // 64*VQN doubles
    float*  am_t = (float*)(cbT + (size_t)64 * VQN);
    float*  sd_t = am_t + (size_t)NC * 128;
    float*  cr_t = sd_t + (size_t)NC * 128;
    float*  e_t  = cr_t + NC;
    int*    idx_t = (int*)(e_t + NC);

    float* out = (float*)d_out;
    const size_t cr_off   = (size_t)B * 256;     // after am (B*128) + sd (B*128)
    const size_t loss_off = cr_off + (size_t)B;
    const size_t idx_off  = loss_off + 1;

    transpose_cb_kernel<<<(64 * VQN + 255) / 256, 256, 0, stream>>>(cb, cbT, VQN);

    per_class_kernel<<<NC, 256, 0, stream>>>(
        embed, W1, b1, W2, b2, W3, b3, Wp, bp, cb, cbT,
        Wa, ba, Ws, bs, Wc1, bc1, Wc2, bc2, Wc3, bc3, Wc4, bc4,
        am_t, sd_t, cr_t, idx_t, e_t, out + loss_off, VQN);

    const int vecBlocks    = (B * 32) / 256;
    const int scalarBlocks = (B + 255) / 256;
    scatter_kernel<<<vecBlocks + scalarBlocks, 256, 0, stream>>>(
        obs, (const f4*)am_t, (const f4*)sd_t, cr_t, idx_t, e_t,
        (f4*)out, out + cr_off, out + idx_off, out + loss_off,
        B, 1.25f / ((float)B * 64.0f));
}

// Round 3
// 267.072 us; speedup vs baseline: 1.4165x; 1.4165x over previous
//
#include <hip/hip_runtime.h>
#include <math.h>

// Outputs are a pure function of obs's class (NC=1000 distinct values):
// compute per-class tables once (fp64 trunk for argmin robustness), then
// scatter per batch element. Memory floor = the 134 MB of mandatory writes.
//
// R6: per_class is serial-latency-bound (12 barrier-separated phases,
// VALUBusy 5.9%). Fix: 2 classes per 128-thread block — every weight load
// feeds 2 FMA chains (2x arithmetic intensity), per-thread ILP doubles,
// barriers per class halve. Per-class chain structure / op order /
// tie-break are bit-identical to the passing R3/R4 kernels => absmax 0.
// cbT transpose kernel dropped (R4 proved VQ coalescing was a null; saves
// a launch). 2 launches total.

typedef float f4 __attribute__((ext_vector_type(4)));

__device__ __forceinline__ float sigmoidf_(float x){ return 1.0f/(1.0f + expf(-x)); }

__global__ __launch_bounds__(128) void per_class_kernel(
    const float* __restrict__ embed,
    const float* __restrict__ W1, const float* __restrict__ b1,
    const float* __restrict__ W2, const float* __restrict__ b2,
    const float* __restrict__ W3, const float* __restrict__ b3,
    const float* __restrict__ Wp, const float* __restrict__ bp,
    const float* __restrict__ cb,
    const float* __restrict__ Wa, const float* __restrict__ ba,
    const float* __restrict__ Ws, const float* __restrict__ bs,
    const float* __restrict__ Wc1, const float* __restrict__ bc1,
    const float* __restrict__ Wc2, const float* __restrict__ bc2,
    const float* __restrict__ Wc3, const float* __restrict__ bc3,
    const float* __restrict__ Wc4, const float* __restrict__ bc4,
    float* __restrict__ am_t, float* __restrict__ sd_t,
    float* __restrict__ cr_t, int* __restrict__ idx_t, float* __restrict__ e_t,
    float* __restrict__ loss_slot, int VQN, int NC)
{
    const int t  = threadIdx.x;                 // 0..127
    const int c0 = blockIdx.x * 2;
    const int c1 = (c0 + 1 < NC) ? c0 + 1 : NC - 1;   // clamp (idempotent dup write)
    if (blockIdx.x == 0 && t == 0) *loss_slot = 0.0f; // d_out is poisoned each call

    __shared__ double A0[128], A1[128];
    __shared__ double B0[128], B1[128];
    __shared__ double zp0[64], zp1[64];
    __shared__ float  qv0[64], qv1[64];
    __shared__ double rdA[128], rdB[128];
    __shared__ int    riA[128], riB[128];
    __shared__ float  h1a[128], h1b[128], h2a[128], h2b[128], h3a[32], h3b[32];

    // y = embed[c]
    A0[t] = (double)embed[(size_t)c0 * 128 + t];
    A1[t] = (double)embed[(size_t)c1 * 128 + t];
    __syncthreads();

    // z1 = relu(y @ W1 + b1) — 4 chains per class, weights loaded once
    {
        double bb = (double)b1[t];
        double aA0 = bb, aA1 = 0.0, aA2 = 0.0, aA3 = 0.0;
        double aB0 = bb, aB1 = 0.0, aB2 = 0.0, aB3 = 0.0;
        for (int i = 0; i < 128; i += 4) {
            double w0 = (double)W1[(i+0) * 128 + t];
            double w1 = (double)W1[(i+1) * 128 + t];
            double w2 = (double)W1[(i+2) * 128 + t];
            double w3 = (double)W1[(i+3) * 128 + t];
            aA0 = fma(A0[i+0], w0, aA0);  aB0 = fma(A1[i+0], w0, aB0);
            aA1 = fma(A0[i+1], w1, aA1);  aB1 = fma(A1[i+1], w1, aB1);
            aA2 = fma(A0[i+2], w2, aA2);  aB2 = fma(A1[i+2], w2, aB2);
            aA3 = fma(A0[i+3], w3, aA3);  aB3 = fma(A1[i+3], w3, aB3);
        }
        double accA = (aA0 + aA1) + (aA2 + aA3);
        double accB = (aB0 + aB1) + (aB2 + aB3);
        B0[t] = accA > 0.0 ? accA : 0.0;
        B1[t] = accB > 0.0 ? accB : 0.0;
    }
    __syncthreads();

    // z2 = relu(z1 @ W2 + b2)
    {
        double bb = (double)b2[t];
        double aA0 = bb, aA1 = 0.0, aA2 = 0.0, aA3 = 0.0;
        double aB0 = bb, aB1 = 0.0, aB2 = 0.0, aB3 = 0.0;
        for (int i = 0; i < 128; i += 4) {
            double w0 = (double)W2[(i+0) * 128 + t];
            double w1 = (double)W2[(i+1) * 128 + t];
            double w2 = (double)W2[(i+2) * 128 + t];
            double w3 = (double)W2[(i+3) * 128 + t];
            aA0 = fma(B0[i+0], w0, aA0);  aB0 = fma(B1[i+0], w0, aB0);
            aA1 = fma(B0[i+1], w1, aA1);  aB1 = fma(B1[i+1], w1, aB1);
            aA2 = fma(B0[i+2], w2, aA2);  aB2 = fma(B1[i+2], w2, aB2);
            aA3 = fma(B0[i+3], w3, aA3);  aB3 = fma(B1[i+3], w3, aB3);
        }
        double accA = (aA0 + aA1) + (aA2 + aA3);
        double accB = (aB0 + aB1) + (aB2 + aB3);
        A0[t] = accA > 0.0 ? accA : 0.0;
        A1[t] = accB > 0.0 ? accB : 0.0;
    }
    __syncthreads();

    // z3 = relu(z2 @ W3 + b3)
    {
        double bb = (double)b3[t];
        double aA0 = bb, aA1 = 0.0, aA2 = 0.0, aA3 = 0.0;
        double aB0 = bb, aB1 = 0.0, aB2 = 0.0, aB3 = 0.0;
        for (int i = 0; i < 128; i += 4) {
            double w0 = (double)W3[(i+0) * 128 + t];
            double w1 = (double)W3[(i+1) * 128 + t];
            double w2 = (double)W3[(i+2) * 128 + t];
            double w3 = (double)W3[(i+3) * 128 + t];
            aA0 = fma(A0[i+0], w0, aA0);  aB0 = fma(A1[i+0], w0, aB0);
            aA1 = fma(A0[i+1], w1, aA1);  aB1 = fma(A1[i+1], w1, aB1);
            aA2 = fma(A0[i+2], w2, aA2);  aB2 = fma(A1[i+2], w2, aB2);
            aA3 = fma(A0[i+3], w3, aA3);  aB3 = fma(A1[i+3], w3, aB3);
        }
        double accA = (aA0 + aA1) + (aA2 + aA3);
        double accB = (aB0 + aB1) + (aB2 + aB3);
        B0[t] = accA > 0.0 ? accA : 0.0;
        B1[t] = accB > 0.0 ? accB : 0.0;
    }
    __syncthreads();

    // zp = z3 @ Wp + bp   (64 outputs per class)
    if (t < 64) {
        double bb = (double)bp[t];
        double aA0 = bb, aA1 = 0.0, aA2 = 0.0, aA3 = 0.0;
        double aB0 = bb, aB1 = 0.0, aB2 = 0.0, aB3 = 0.0;
        for (int i = 0; i < 128; i += 4) {
            double w0 = (double)Wp[(i+0) * 64 + t];
            double w1 = (double)Wp[(i+1) * 64 + t];
            double w2 = (double)Wp[(i+2) * 64 + t];
            double w3 = (double)Wp[(i+3) * 64 + t];
            aA0 = fma(B0[i+0], w0, aA0);  aB0 = fma(B1[i+0], w0, aB0);
            aA1 = fma(B0[i+1], w1, aA1);  aB1 = fma(B1[i+1], w1, aB1);
            aA2 = fma(B0[i+2], w2, aA2);  aB2 = fma(B1[i+2], w2, aB2);
            aA3 = fma(B0[i+3], w3, aA3);  aB3 = fma(B1[i+3], w3, aB3);
        }
        zp0[t] = (aA0 + aA1) + (aA2 + aA3);
        zp1[t] = (aB0 + aB1) + (aB2 + aB3);
    }
    __syncthreads();

    // VQ argmin: thread t owns codes t, t+128, ...; codebook row loaded
    // once, distance chains per class bit-identical to R3 (even/odd, fp64,
    // strict-< first-min in ascending k).
    double bestA = 1e300, bestB = 1e300; int biA = 0, biB = 0;
    for (int k = t; k < VQN; k += 128) {
        const float* crow = cb + (size_t)k * 64;
        double sA0 = 0.0, sA1 = 0.0, sB0 = 0.0, sB1 = 0.0;
        for (int j = 0; j < 64; j += 2) {
            double w0 = (double)crow[j+0];
            double w1 = (double)crow[j+1];
            double dA0 = zp0[j+0] - w0, dA1 = zp0[j+1] - w1;
            double dB0 = zp1[j+0] - w0, dB1 = zp1[j+1] - w1;
            sA0 = fma(dA0, dA0, sA0);  sA1 = fma(dA1, dA1, sA1);
            sB0 = fma(dB0, dB0, sB0);  sB1 = fma(dB1, dB1, sB1);
        }
        double sA = sA0 + sA1, sB = sB0 + sB1;
        if (sA < bestA) { bestA = sA; biA = k; }
        if (sB < bestB) { bestB = sB; biB = k; }
    }
    rdA[t] = bestA; riA[t] = biA;
    rdB[t] = bestB; riB[t] = biB;
    __syncthreads();
    for (int sft = 64; sft > 0; sft >>= 1) {
        if (t < sft) {
            if (rdA[t + sft] < rdA[t] || (rdA[t + sft] == rdA[t] && riA[t + sft] < riA[t])) {
                rdA[t] = rdA[t + sft]; riA[t] = riA[t + sft];
            }
            if (rdB[t + sft] < rdB[t] || (rdB[t + sft] == rdB[t] && riB[t + sft] < riB[t])) {
                rdB[t] = rdB[t + sft]; riB[t] = riB[t + sft];
            }
        }
        __syncthreads();
    }
    const int widxA = riA[0];
    const int widxB = riB[0];
    if (t < 64) qv0[t] = cb[(size_t)widxA * 64 + t];
    else        qv1[t - 64] = cb[(size_t)widxB * 64 + (t - 64)];
    __syncthreads();

    // heads (fp32; q = exact codebook row); weights loaded once per pair
    {
        float la_A0 = ba[t],  la_A1 = 0.0f, la_B0 = ba[t],  la_B1 = 0.0f;
        float ls_A0 = bs[t],  ls_A1 = 0.0f, ls_B0 = bs[t],  ls_B1 = 0.0f;
        float l1_A0 = bc1[t], l1_A1 = 0.0f, l1_B0 = bc1[t], l1_B1 = 0.0f;
        for (int j = 0; j < 64; j += 2) {
            float wa0 = Wa[j * 128 + t],  wa1 = Wa[(j+1) * 128 + t];
            float ws0 = Ws[j * 128 + t],  ws1 = Ws[(j+1) * 128 + t];
            float wc0 = Wc1[j * 128 + t], wc1 = Wc1[(j+1) * 128 + t];
            float qA0 = qv0[j], qA1 = qv0[j+1];
            float qB0 = qv1[j], qB1 = qv1[j+1];
            la_A0 = fmaf(qA0, wa0, la_A0);  la_A1 = fmaf(qA1, wa1, la_A1);
            la_B0 = fmaf(qB0, wa0, la_B0);  la_B1 = fmaf(qB1, wa1, la_B1);
            ls_A0 = fmaf(qA0, ws0, ls_A0);  ls_A1 = fmaf(qA1, ws1, ls_A1);
            ls_B0 = fmaf(qB0, ws0, ls_B0);  ls_B1 = fmaf(qB1, ws1, ls_B1);
            l1_A0 = fmaf(qA0, wc0, l1_A0);  l1_A1 = fmaf(qA1, wc1, l1_A1);
            l1_B0 = fmaf(qB0, wc0, l1_B0);  l1_B1 = fmaf(qB1, wc1, l1_B1);
        }
        am_t[(size_t)c0 * 128 + t] = sigmoidf_(la_A0 + la_A1);
        am_t[(size_t)c1 * 128 + t] = sigmoidf_(la_B0 + la_B1);
        sd_t[(size_t)c0 * 128 + t] = sigmoidf_(ls_A0 + ls_A1) * 1.0f + 1e-8f;  // SQUISH=1.0
        sd_t[(size_t)c1 * 128 + t] = sigmoidf_(ls_B0 + ls_B1) * 1.0f + 1e-8f;
        h1a[t] = sigmoidf_(l1_A0 + l1_A1);
        h1b[t] = sigmoidf_(l1_B0 + l1_B1);
    }
    __syncthreads();

    // critic layer 2 (128->128)
    {
        float lA0 = bc2[t], lA1 = 0.0f, lB0 = bc2[t], lB1 = 0.0f;
        for (int i = 0; i < 128; i += 2) {
            float w0 = Wc2[i * 128 + t], w1 = Wc2[(i+1) * 128 + t];
            lA0 = fmaf(h1a[i],   w0, lA0);  lA1 = fmaf(h1a[i+1], w1, lA1);
            lB0 = fmaf(h1b[i],   w0, lB0);  lB1 = fmaf(h1b[i+1], w1, lB1);
        }
        h2a[t] = sigmoidf_(lA0 + lA1);
        h2b[t] = sigmoidf_(lB0 + lB1);
    }
    __syncthreads();

    // critic layer 3 (128->32)
    if (t < 32) {
        float lA0 = bc3[t], lA1 = 0.0f, lB0 = bc3[t], lB1 = 0.0f;
        for (int i = 0; i < 128; i += 2) {
            float w0 = Wc3[i * 32 + t], w1 = Wc3[(i+1) * 32 + t];
            lA0 = fmaf(h2a[i],   w0, lA0);  lA1 = fmaf(h2a[i+1], w1, lA1);
            lB0 = fmaf(h2b[i],   w0, lB0);  lB1 = fmaf(h2b[i+1], w1, lB1);
        }
        h3a[t] = sigmoidf_(lA0 + lA1);
        h3b[t] = sigmoidf_(lB0 + lB1);
    }
    __syncthreads();

    // per-class epilogues on separate waves (t==0: class A, t==64: class B)
    if (t == 0) {
        float l4 = bc4[0];
        for (int i = 0; i < 32; ++i) l4 = fmaf(h3a[i], Wc4[i], l4);
        cr_t[c0] = l4;             // no sigmoid on final critic layer
        idx_t[c0] = widxA;
        double e0 = 0.0, e1 = 0.0;
        for (int j = 0; j < 64; j += 2) {
            double d0 = (double)qv0[j]   - zp0[j];
            double d1 = (double)qv0[j+1] - zp0[j+1];
            e0 = fma(d0, d0, e0); e1 = fma(d1, d1, e1);
        }
        e_t[c0] = (float)(e0 + e1);
    }
    if (t == 64 && c1 != c0) {
        float l4 = bc4[0];
        for (int i = 0; i < 32; ++i) l4 = fmaf(h3b[i], Wc4[i], l4);
        cr_t[c1] = l4;
        idx_t[c1] = widxB;
        double e0 = 0.0, e1 = 0.0;
        for (int j = 0; j < 64; j += 2) {
            double d0 = (double)qv1[j]   - zp1[j];
            double d1 = (double)qv1[j+1] - zp1[j+1];
            e0 = fma(d0, d0, e0); e1 = fma(d1, d1, e1);
        }
        e_t[c1] = (float)(e0 + e1);
    }
}

// Merged scatter: blocks [0, vecBlocks) emit BOTH am and sd float4 per
// thread from one obs read (coalesced nontemporal); trailing blocks do
// the critic/idx scatter and vq_loss reduction (one atomic per block).
__global__ __launch_bounds__(256) void scatter_kernel(
    const int* __restrict__ obs,
    const f4* __restrict__ am_t, const f4* __restrict__ sd_t,
    const float* __restrict__ cr_t, const int* __restrict__ idx_t,
    const float* __restrict__ e_t,
    f4* __restrict__ out_vec, float* __restrict__ out_critic,
    float* __restrict__ out_idx, float* __restrict__ out_loss,
    int B, float scale)
{
    __shared__ float red[256];
    const int vecBlocks = (B * 32) / 256;           // B*128/4 f4-slots per half
    if ((int)blockIdx.x < vecBlocks) {
        int gid = blockIdx.x * 256 + threadIdx.x;
        int b = gid >> 5;                           // 32 float4 per row
        int j = gid & 31;
        size_t row = (size_t)obs[b] * 32 + j;
        __builtin_nontemporal_store(am_t[row], &out_vec[gid]);
        __builtin_nontemporal_store(sd_t[row], &out_vec[(size_t)B * 32 + gid]);
        return;
    }
    int b = (blockIdx.x - vecBlocks) * 256 + threadIdx.x;
    float e = 0.0f;
    if (b < B) {
        int o = obs[b];
        __builtin_nontemporal_store(cr_t[o], &out_critic[b]);
        __builtin_nontemporal_store((float)idx_t[o], &out_idx[b]);
        e = e_t[o];
    }
    red[threadIdx.x] = e;
    __syncthreads();
    for (int s = 128; s > 0; s >>= 1) {
        if (threadIdx.x < s) red[threadIdx.x] += red[threadIdx.x + s];
        __syncthreads();
    }
    if (threadIdx.x == 0) atomicAdd(out_loss, red[0] * scale);
}

extern "C" void kernel_launch(void* const* d_in, const int* in_sizes, int n_in,
                              void* d_out, int out_size, void* d_ws, size_t ws_size,
                              hipStream_t stream)
{
    const int*   obs   = (const int*)  d_in[0];
    const float* embed = (const float*)d_in[1];
    const float* W1    = (const float*)d_in[2];
    const float* b1    = (const float*)d_in[3];
    const float* W2    = (const float*)d_in[4];
    const float* b2    = (const float*)d_in[5];
    const float* W3    = (const float*)d_in[6];
    const float* b3    = (const float*)d_in[7];
    const float* Wp    = (const float*)d_in[8];
    const float* bp    = (const float*)d_in[9];
    const float* cb    = (const float*)d_in[10];
    const float* Wa    = (const float*)d_in[11];
    const float* ba    = (const float*)d_in[12];
    const float* Ws    = (const float*)d_in[13];
    const float* bs    = (const float*)d_in[14];
    const float* Wc1   = (const float*)d_in[15];
    const float* bc1   = (const float*)d_in[16];
    const float* Wc2   = (const float*)d_in[17];
    const float* bc2   = (const float*)d_in[18];
    const float* Wc3   = (const float*)d_in[19];
    const float* bc3   = (const float*)d_in[20];
    const float* Wc4   = (const float*)d_in[21];
    const float* bc4   = (const float*)d_in[22];

    const int B   = in_sizes[0];
    const int NC  = in_sizes[1] / 128;
    const int VQN = in_sizes[10] / 64;

    // workspace tables (~1.04 MB for NC=1000)
    float* am_t = (float*)d_ws;
    float* sd_t = am_t + (size_t)NC * 128;
    float* cr_t = sd_t + (size_t)NC * 128;
    float* e_t  = cr_t + NC;
    int*   idx_t = (int*)(e_t + NC);

    float* out = (float*)d_out;
    const size_t cr_off   = (size_t)B * 256;     // after am (B*128) + sd (B*128)
    const size_t loss_off = cr_off + (size_t)B;
    const size_t idx_off  = loss_off + 1;

    per_class_kernel<<<(NC + 1) / 2, 128, 0, stream>>>(
        embed, W1, b1, W2, b2, W3, b3, Wp, bp, cb,
        Wa, ba, Ws, bs, Wc1, bc1, Wc2, bc2, Wc3, bc3, Wc4, bc4,
        am_t, sd_t, cr_t, idx_t, e_t, out + loss_off, VQN, NC);

    const int vecBlocks    = (B * 32) / 256;
    const int scalarBlocks = (B + 255) / 256;
    scatter_kernel<<<vecBlocks + scalarBlocks, 256, 0, stream>>>(
        obs, (const f4*)am_t, (const f4*)sd_t, cr_t, idx_t, e_t,
        (f4*)out, out + cr_off, out + idx_off, out + loss_off,
        B, 1.25f / ((float)B * 64.0f));
}

// Round 4
// 240.448 us; speedup vs baseline: 1.5733x; 1.1107x over previous
//
#include <hip/hip_runtime.h>
#include <math.h>

// Outputs are a pure function of obs's class (NC=1000 distinct values):
// compute per-class tables once (fp64 trunk for argmin robustness), then
// scatter per batch element. Memory floor = the 134 MB of mandatory writes.
//
// R7: all blocks are co-resident (one round), so total ≈ per-block serial
// latency ≈ Σ phases (loads/thread ÷ outstanding) × L2 latency. Cut
// loads/thread 4x with float4 weight loads by mapping R3's 4-FMA-chain
// structure onto threads: thread (h,q) computes chain h (i ≡ h mod 4) of
// outputs 4q..4q+3; partials combine as (a0+a1)+(a2+a3) — bit-identical
// per-output math => absmax 0. Heads/c2/c3 keep their 2-chain (even/odd)
// structure with f4/f2 loads. VQ rows read as float4 with R3's exact
// s0/s1 accumulation order; reduce is an order-independent (min d, min
// idx) shuffle lattice. 1 class/block, 1000 blocks, 128 threads.

typedef float f4 __attribute__((ext_vector_type(4)));
typedef float f2 __attribute__((ext_vector_type(2)));

__device__ __forceinline__ float sigmoidf_(float x){ return 1.0f/(1.0f + expf(-x)); }

__global__ __launch_bounds__(128) void per_class_kernel(
    const float* __restrict__ embed,
    const float* __restrict__ W1, const float* __restrict__ b1,
    const float* __restrict__ W2, const float* __restrict__ b2,
    const float* __restrict__ W3, const float* __restrict__ b3,
    const float* __restrict__ Wp, const float* __restrict__ bp,
    const float* __restrict__ cb,
    const float* __restrict__ Wa, const float* __restrict__ ba,
    const float* __restrict__ Ws, const float* __restrict__ bs,
    const float* __restrict__ Wc1, const float* __restrict__ bc1,
    const float* __restrict__ Wc2, const float* __restrict__ bc2,
    const float* __restrict__ Wc3, const float* __restrict__ bc3,
    const float* __restrict__ Wc4, const float* __restrict__ bc4,
    float* __restrict__ am_t, float* __restrict__ sd_t,
    float* __restrict__ cr_t, int* __restrict__ idx_t, float* __restrict__ e_t,
    float* __restrict__ loss_slot, int VQN)
{
    const int c = blockIdx.x;
    const int t = threadIdx.x;           // 0..127
    if (c == 0 && t == 0) *loss_slot = 0.0f;   // d_out is poisoned each call

    __shared__ double Ain[128], Bin[128];
    __shared__ double part[4][128];
    __shared__ double zp[64];
    __shared__ float  qv[64];
    __shared__ double rds[2];
    __shared__ int    ris[2];
    __shared__ int    widx_s;
    __shared__ float  fpart[4][128];
    __shared__ float  gpart[2][128];
    __shared__ float  h1[128], h2[128], h3[32];

    const int q4 = (t & 31) << 2;        // output base (4 outputs/thread)
    const int h  = t >> 5;               // K-chain 0..3 (i ≡ h mod 4)

    // y = embed[c]
    Ain[t] = (double)embed[(size_t)c * 128 + t];
    __syncthreads();

    // ---- trunk layer macro: chain h of outputs q4..q4+3, f4 weight loads.
    // Chain 0 carries the bias (matches R3's a0 = b[t] init). Combine is
    // (a0+a1)+(a2+a3) then ReLU — bit-identical to R3.
#define TRUNK_LAYER(W, B, IN, OUT)                                          \
    {                                                                       \
        double a0 = (h == 0) ? (double)B[q4+0] : 0.0;                       \
        double a1 = (h == 0) ? (double)B[q4+1] : 0.0;                       \
        double a2 = (h == 0) ? (double)B[q4+2] : 0.0;                       \
        double a3 = (h == 0) ? (double)B[q4+3] : 0.0;                       \
        for (int s = 0; s < 32; ++s) {                                      \
            int i = h + (s << 2);                                           \
            f4 w = *(const f4*)(W + (size_t)i * 128 + q4);                  \
            double x = IN[i];                                               \
            a0 = fma(x, (double)w.x, a0);                                   \
            a1 = fma(x, (double)w.y, a1);                                   \
            a2 = fma(x, (double)w.z, a2);                                   \
            a3 = fma(x, (double)w.w, a3);                                   \
        }                                                                   \
        part[h][q4+0] = a0; part[h][q4+1] = a1;                             \
        part[h][q4+2] = a2; part[h][q4+3] = a3;                             \
    }                                                                       \
    __syncthreads();                                                        \
    {                                                                       \
        double acc = (part[0][t] + part[1][t]) + (part[2][t] + part[3][t]); \
        OUT[t] = acc > 0.0 ? acc : 0.0;                                     \
    }                                                                       \
    __syncthreads();

    TRUNK_LAYER(W1, b1, Ain, Bin)
    TRUNK_LAYER(W2, b2, Bin, Ain)
    TRUNK_LAYER(W3, b3, Ain, Bin)
#undef TRUNK_LAYER

    // zp = z3 @ Wp + bp (64 outputs): 16 q-groups x 4 chains, t<64 active
    if (t < 64) {
        const int q4p = (t & 15) << 2;
        const int hp  = t >> 4;          // 0..3
        double a0 = (hp == 0) ? (double)bp[q4p+0] : 0.0;
        double a1 = (hp == 0) ? (double)bp[q4p+1] : 0.0;
        double a2 = (hp == 0) ? (double)bp[q4p+2] : 0.0;
        double a3 = (hp == 0) ? (double)bp[q4p+3] : 0.0;
        for (int s = 0; s < 32; ++s) {
            int i = hp + (s << 2);
            f4 w = *(const f4*)(Wp + (size_t)i * 64 + q4p);
            double x = Bin[i];
            a0 = fma(x, (double)w.x, a0);
            a1 = fma(x, (double)w.y, a1);
            a2 = fma(x, (double)w.z, a2);
            a3 = fma(x, (double)w.w, a3);
        }
        part[hp][q4p+0] = a0; part[hp][q4p+1] = a1;
        part[hp][q4p+2] = a2; part[hp][q4p+3] = a3;
    }
    __syncthreads();
    if (t < 64) zp[t] = (part[0][t] + part[1][t]) + (part[2][t] + part[3][t]);
    __syncthreads();

    // VQ argmin: thread t owns codes t, t+128, ...; f4 row loads, s0/s1
    // accumulation order identical to R3 (s0: j=0,2,4..; s1: j=1,3,5..).
    double best = 1e300; int bidx = 0;
    for (int k = t; k < VQN; k += 128) {
        const float* crow = cb + (size_t)k * 64;
        double s0 = 0.0, s1 = 0.0;
        for (int j = 0; j < 64; j += 4) {
            f4 v = *(const f4*)(crow + j);
            double d0 = zp[j+0] - (double)v.x;
            double d1 = zp[j+1] - (double)v.y;
            double d2 = zp[j+2] - (double)v.z;
            double d3 = zp[j+3] - (double)v.w;
            s0 = fma(d0, d0, s0);  s1 = fma(d1, d1, s1);
            s0 = fma(d2, d2, s0);  s1 = fma(d3, d3, s1);
        }
        double s = s0 + s1;
        if (s < best) { best = s; bidx = k; }   // first-min, ascending k
    }
    // (min d, min idx) lattice reduce — order-independent, same result as
    // the R3 LDS tree with tie-break.
    for (int off = 32; off > 0; off >>= 1) {
        double od = __shfl_down(best, off);
        int    oi = __shfl_down(bidx, off);
        if (od < best || (od == best && oi < bidx)) { best = od; bidx = oi; }
    }
    if ((t & 63) == 0) { rds[t >> 6] = best; ris[t >> 6] = bidx; }
    __syncthreads();
    if (t == 0) {
        double b0 = rds[0]; int i0 = ris[0];
        if (rds[1] < b0 || (rds[1] == b0 && ris[1] < i0)) { i0 = ris[1]; }
        widx_s = i0;
    }
    __syncthreads();
    const int widx = widx_s;
    if (t < 64) qv[t] = cb[(size_t)widx * 64 + t];
    __syncthreads();

    // heads H1: slots (t>>5): 0=Wa-even, 1=Wa-odd, 2=Ws-even, 3=Ws-odd.
    // Chain even carries the bias (matches R3's la0/ls0 init).
    {
        const int m  = t >> 6;           // 0: Wa, 1: Ws
        const int hh = (t >> 5) & 1;     // chain parity
        const float* Wm = m ? Ws : Wa;
        const float* bm = m ? bs : ba;
        float a0 = hh ? 0.0f : bm[q4+0];
        float a1 = hh ? 0.0f : bm[q4+1];
        float a2 = hh ? 0.0f : bm[q4+2];
        float a3 = hh ? 0.0f : bm[q4+3];
        for (int s = 0; s < 32; ++s) {
            int j = hh + (s << 1);
            f4 w = *(const f4*)(Wm + (size_t)j * 128 + q4);
            float qj = qv[j];
            a0 = fmaf(qj, w.x, a0);
            a1 = fmaf(qj, w.y, a1);
            a2 = fmaf(qj, w.z, a2);
            a3 = fmaf(qj, w.w, a3);
        }
        fpart[t >> 5][q4+0] = a0; fpart[t >> 5][q4+1] = a1;
        fpart[t >> 5][q4+2] = a2; fpart[t >> 5][q4+3] = a3;
    }
    __syncthreads();

    // H2: t<64 compute Wc1 (even/odd chains); t>=64 combine+store am/sd.
    if (t < 64) {
        const int hh = t >> 5;           // 0,1
        float a0 = hh ? 0.0f : bc1[q4+0];
        float a1 = hh ? 0.0f : bc1[q4+1];
        float a2 = hh ? 0.0f : bc1[q4+2];
        float a3 = hh ? 0.0f : bc1[q4+3];
        for (int s = 0; s < 32; ++s) {
            int j = hh + (s << 1);
            f4 w = *(const f4*)(Wc1 + (size_t)j * 128 + q4);
            float qj = qv[j];
            a0 = fmaf(qj, w.x, a0);
            a1 = fmaf(qj, w.y, a1);
            a2 = fmaf(qj, w.z, a2);
            a3 = fmaf(qj, w.w, a3);
        }
        gpart[hh][q4+0] = a0; gpart[hh][q4+1] = a1;
        gpart[hh][q4+2] = a2; gpart[hh][q4+3] = a3;
    } else {
        int o = (t - 64) << 1;
        am_t[(size_t)c * 128 + o]     = sigmoidf_(fpart[0][o]   + fpart[1][o]);
        am_t[(size_t)c * 128 + o + 1] = sigmoidf_(fpart[0][o+1] + fpart[1][o+1]);
        sd_t[(size_t)c * 128 + o]     = sigmoidf_(fpart[2][o]   + fpart[3][o])   * 1.0f + 1e-8f;
        sd_t[(size_t)c * 128 + o + 1] = sigmoidf_(fpart[2][o+1] + fpart[3][o+1]) * 1.0f + 1e-8f;
    }
    __syncthreads();
    h1[t] = sigmoidf_(gpart[0][t] + gpart[1][t]);
    __syncthreads();

    // critic layer 2 (128->128): 64 o-pairs x 2 chains, f2 loads
    {
        const int o2 = (t & 63) << 1;
        const int hh = t >> 6;
        float a0 = hh ? 0.0f : bc2[o2+0];
        float a1 = hh ? 0.0f : bc2[o2+1];
        for (int s = 0; s < 64; ++s) {
            int i = hh + (s << 1);
            f2 w = *(const f2*)(Wc2 + (size_t)i * 128 + o2);
            float x = h1[i];
            a0 = fmaf(x, w.x, a0);
            a1 = fmaf(x, w.y, a1);
        }
        gpart[hh][o2+0] = a0; gpart[hh][o2+1] = a1;
    }
    __syncthreads();
    h2[t] = sigmoidf_(gpart[0][t] + gpart[1][t]);
    __syncthreads();

    // critic layer 3 (128->32): 16 o-pairs x 2 chains, f2 loads, t<32
    if (t < 32) {
        const int o2 = (t & 15) << 1;
        const int hh = t >> 4;
        float a0 = hh ? 0.0f : bc3[o2+0];
        float a1 = hh ? 0.0f : bc3[o2+1];
        for (int s = 0; s < 64; ++s) {
            int i = hh + (s << 1);
            f2 w = *(const f2*)(Wc3 + (size_t)i * 32 + o2);
            float x = h2[i];
            a0 = fmaf(x, w.x, a0);
            a1 = fmaf(x, w.y, a1);
        }
        gpart[hh][o2+0] = a0; gpart[hh][o2+1] = a1;
    }
    __syncthreads();
    if (t < 32) h3[t] = sigmoidf_(gpart[0][t] + gpart[1][t]);
    __syncthreads();

    if (t == 0) {
        float l4 = bc4[0];
        for (int i = 0; i < 32; ++i) l4 = fmaf(h3[i], Wc4[i], l4);
        cr_t[c] = l4;              // no sigmoid on final critic layer
        idx_t[c] = widx;
        double e0 = 0.0, e1 = 0.0;
        for (int j = 0; j < 64; j += 2) {
            double d0 = (double)qv[j]   - zp[j];
            double d1 = (double)qv[j+1] - zp[j+1];
            e0 = fma(d0, d0, e0); e1 = fma(d1, d1, e1);
        }
        e_t[c] = (float)(e0 + e1); // sum over 64 dims of (quant-z)^2
    }
}

// Merged scatter: blocks [0, vecBlocks) emit BOTH am and sd float4 per
// thread from one obs read (coalesced nontemporal); trailing blocks do
// the critic/idx scatter and vq_loss reduction (one atomic per block).
__global__ __launch_bounds__(256) void scatter_kernel(
    const int* __restrict__ obs,
    const f4* __restrict__ am_t, const f4* __restrict__ sd_t,
    const float* __restrict__ cr_t, const int* __restrict__ idx_t,
    const float* __restrict__ e_t,
    f4* __restrict__ out_vec, float* __restrict__ out_critic,
    float* __restrict__ out_idx, float* __restrict__ out_loss,
    int B, float scale)
{
    __shared__ float red[256];
    const int vecBlocks = (B * 32) / 256;           // B*128/4 f4-slots per half
    if ((int)blockIdx.x < vecBlocks) {
        int gid = blockIdx.x * 256 + threadIdx.x;
        int b = gid >> 5;                           // 32 float4 per row
        int j = gid & 31;
        size_t row = (size_t)obs[b] * 32 + j;
        __builtin_nontemporal_store(am_t[row], &out_vec[gid]);
        __builtin_nontemporal_store(sd_t[row], &out_vec[(size_t)B * 32 + gid]);
        return;
    }
    int b = (blockIdx.x - vecBlocks) * 256 + threadIdx.x;
    float e = 0.0f;
    if (b < B) {
        int o = obs[b];
        __builtin_nontemporal_store(cr_t[o], &out_critic[b]);
        __builtin_nontemporal_store((float)idx_t[o], &out_idx[b]);
        e = e_t[o];
    }
    red[threadIdx.x] = e;
    __syncthreads();
    for (int s = 128; s > 0; s >>= 1) {
        if (threadIdx.x < s) red[threadIdx.x] += red[threadIdx.x + s];
        __syncthreads();
    }
    if (threadIdx.x == 0) atomicAdd(out_loss, red[0] * scale);
}

extern "C" void kernel_launch(void* const* d_in, const int* in_sizes, int n_in,
                              void* d_out, int out_size, void* d_ws, size_t ws_size,
                              hipStream_t stream)
{
    const int*   obs   = (const int*)  d_in[0];
    const float* embed = (const float*)d_in[1];
    const float* W1    = (const float*)d_in[2];
    const float* b1    = (const float*)d_in[3];
    const float* W2    = (const float*)d_in[4];
    const float* b2    = (const float*)d_in[5];
    const float* W3    = (const float*)d_in[6];
    const float* b3    = (const float*)d_in[7];
    const float* Wp    = (const float*)d_in[8];
    const float* bp    = (const float*)d_in[9];
    const float* cb    = (const float*)d_in[10];
    const float* Wa    = (const float*)d_in[11];
    const float* ba    = (const float*)d_in[12];
    const float* Ws    = (const float*)d_in[13];
    const float* bs    = (const float*)d_in[14];
    const float* Wc1   = (const float*)d_in[15];
    const float* bc1   = (const float*)d_in[16];
    const float* Wc2   = (const float*)d_in[17];
    const float* bc2   = (const float*)d_in[18];
    const float* Wc3   = (const float*)d_in[19];
    const float* bc3   = (const float*)d_in[20];
    const float* Wc4   = (const float*)d_in[21];
    const float* bc4   = (const float*)d_in[22];

    const int B   = in_sizes[0];
    const int NC  = in_sizes[1] / 128;
    const int VQN = in_sizes[10] / 64;

    // workspace tables (~1.04 MB for NC=1000)
    float* am_t = (float*)d_ws;
    float* sd_t = am_t + (size_t)NC * 128;
    float* cr_t = sd_t + (size_t)NC * 128;
    float* e_t  = cr_t + NC;
    int*   idx_t = (int*)(e_t + NC);

    float* out = (float*)d_out;
    const size_t cr_off   = (size_t)B * 256;     // after am (B*128) + sd (B*128)
    const size_t loss_off = cr_off + (size_t)B;
    const size_t idx_off  = loss_off + 1;

    per_class_kernel<<<NC, 128, 0, stream>>>(
        embed, W1, b1, W2, b2, W3, b3, Wp, bp, cb,
        Wa, ba, Ws, bs, Wc1, bc1, Wc2, bc2, Wc3, bc3, Wc4, bc4,
        am_t, sd_t, cr_t, idx_t, e_t, out + loss_off, VQN);

    const int vecBlocks    = (B * 32) / 256;
    const int scalarBlocks = (B + 255) / 256;
    scatter_kernel<<<vecBlocks + scalarBlocks, 256, 0, stream>>>(
        obs, (const f4*)am_t, (const f4*)sd_t, cr_t, idx_t, e_t,
        (f4*)out, out + cr_off, out + idx_off, out + loss_off,
        B, 1.25f / ((float)B * 64.0f));
}

// Round 5
// 239.173 us; speedup vs baseline: 1.5817x; 1.0053x over previous
//
#include <hip/hip_runtime.h>
#include <math.h>

// Outputs are a pure function of obs's class (NC=1000 distinct values),
// and the heads (am/sd/critic) are a pure function of the VQ CODE
// (VQN=512 distinct values). R8 structure:
//   fused compute kernel, block-range split:
//     blocks [0, NC/2):        trunk+VQ for 2 classes, SHARED f4 weight
//                              loads (8 K-chains x 16 f4 loads/thread,
//                              each load feeds both classes); VQ shares
//                              each codebook row across both classes.
//                              -> idx_t[c], e_t[c]
//     blocks [NC/2, +VQN/2):   heads per CODE (2 codes/block, 128-thread
//                              groups, verbatim R7 head code => outputs
//                              bit-identical to R7) -> am_c/sd_c/cr_c[k]
//   scatter: out[b] = tables[idx_t[obs[b]]] (one extra L1-hot indirection)
// fp64 trunk summation order differs from R7 at ~1e-16 — far below the
// fp32 reference's own argmin noise, so idx is stable (same argument that
// justified the fp64 trunk originally).

typedef float f4 __attribute__((ext_vector_type(4)));
typedef float f2 __attribute__((ext_vector_type(2)));

__device__ __forceinline__ float sigmoidf_(float x){ return 1.0f/(1.0f + expf(-x)); }

__global__ __launch_bounds__(256) void compute_kernel(
    const float* __restrict__ embed,
    const float* __restrict__ W1, const float* __restrict__ b1,
    const float* __restrict__ W2, const float* __restrict__ b2,
    const float* __restrict__ W3, const float* __restrict__ b3,
    const float* __restrict__ Wp, const float* __restrict__ bp,
    const float* __restrict__ cb,
    const float* __restrict__ Wa, const float* __restrict__ ba,
    const float* __restrict__ Ws, const float* __restrict__ bs,
    const float* __restrict__ Wc1, const float* __restrict__ bc1,
    const float* __restrict__ Wc2, const float* __restrict__ bc2,
    const float* __restrict__ Wc3, const float* __restrict__ bc3,
    const float* __restrict__ Wc4, const float* __restrict__ bc4,
    float* __restrict__ am_c, float* __restrict__ sd_c,
    float* __restrict__ cr_c, int* __restrict__ idx_t, float* __restrict__ e_t,
    float* __restrict__ loss_slot, int VQN, int NC, int nTB)
{
    const int bid = blockIdx.x;
    const int t   = threadIdx.x;     // 0..255
    if (bid == 0 && t == 0) *loss_slot = 0.0f;   // d_out is poisoned each call

    // trunk-branch LDS
    __shared__ double U[2][128], V[2][128];     // layer ping-pong (class A/B)
    __shared__ double part[2][8][128];          // fp64 chain partials
    __shared__ double zp2[2][64];
    __shared__ float  qv2[2][64];
    __shared__ double rda[2][4];
    __shared__ int    ria[2][4];
    __shared__ int    widx2[2];
    // head-branch LDS
    __shared__ float  qvh[2][64];
    __shared__ float  fpart[2][4][128];
    __shared__ float  gpart[2][2][128];
    __shared__ float  h1s[2][128], h2s[2][128], h3s[2][32];

    if (bid < nTB) {
        // ================= trunk + VQ for classes c0, c1 =================
        const int c0  = bid * 2;
        const int c1  = (c0 + 1 < NC) ? c0 + 1 : NC - 1;   // clamp (dup-safe)
        const int cls = t >> 7;          // this thread's class for combines
        const int r   = t & 127;
        const int q4  = (t & 31) << 2;   // output quad (shared-load phases)
        const int h   = t >> 5;          // K-chain 0..7 (i ≡ h mod 8)

        if (t < 128) U[0][t] = (double)embed[(size_t)c0 * 128 + t];
        else         U[1][r] = (double)embed[(size_t)c1 * 128 + r];
        __syncthreads();

        // trunk layer: thread (h,q4) computes chain h of outputs q4..q4+3
        // for BOTH classes from one f4 weight load. Chain 0 carries bias.
#define TRUNK2(Wm, bv, IN, OUT)                                               \
        {                                                                     \
            double aA0 = (h == 0) ? (double)bv[q4+0] : 0.0;                   \
            double aA1 = (h == 0) ? (double)bv[q4+1] : 0.0;                   \
            double aA2 = (h == 0) ? (double)bv[q4+2] : 0.0;                   \
            double aA3 = (h == 0) ? (double)bv[q4+3] : 0.0;                   \
            double aB0 = aA0, aB1 = aA1, aB2 = aA2, aB3 = aA3;                \
            _Pragma("unroll")                                                 \
            for (int s = 0; s < 16; ++s) {                                    \
                int i = h + (s << 3);                                         \
                f4 w = *(const f4*)(Wm + (size_t)i * 128 + q4);               \
                double w0 = (double)w.x, w1 = (double)w.y;                    \
                double w2 = (double)w.z, w3 = (double)w.w;                    \
                double xA = IN[0][i], xB = IN[1][i];                          \
                aA0 = fma(xA, w0, aA0);  aB0 = fma(xB, w0, aB0);              \
                aA1 = fma(xA, w1, aA1);  aB1 = fma(xB, w1, aB1);              \
                aA2 = fma(xA, w2, aA2);  aB2 = fma(xB, w2, aB2);              \
                aA3 = fma(xA, w3, aA3);  aB3 = fma(xB, w3, aB3);              \
            }                                                                 \
            part[0][h][q4+0] = aA0; part[0][h][q4+1] = aA1;                   \
            part[0][h][q4+2] = aA2; part[0][h][q4+3] = aA3;                   \
            part[1][h][q4+0] = aB0; part[1][h][q4+1] = aB1;                   \
            part[1][h][q4+2] = aB2; part[1][h][q4+3] = aB3;                   \
        }                                                                     \
        __syncthreads();                                                      \
        {                                                                     \
            double acc = ((part[cls][0][r] + part[cls][1][r])                 \
                        + (part[cls][2][r] + part[cls][3][r]))                \
                       + ((part[cls][4][r] + part[cls][5][r])                 \
                        + (part[cls][6][r] + part[cls][7][r]));               \
            OUT[cls][r] = acc > 0.0 ? acc : 0.0;                              \
        }                                                                     \
        __syncthreads();

        TRUNK2(W1, b1, U, V)
        TRUNK2(W2, b2, V, U)
        TRUNK2(W3, b3, U, V)
#undef TRUNK2

        // zp = z3 @ Wp + bp (64 outs/class): per class 8 chains x 16 quads
        {
            const int q4p = (r & 15) << 2;
            const int hp  = r >> 4;          // 0..7
            double a0 = (hp == 0) ? (double)bp[q4p+0] : 0.0;
            double a1 = (hp == 0) ? (double)bp[q4p+1] : 0.0;
            double a2 = (hp == 0) ? (double)bp[q4p+2] : 0.0;
            double a3 = (hp == 0) ? (double)bp[q4p+3] : 0.0;
            #pragma unroll
            for (int s = 0; s < 16; ++s) {
                int i = hp + (s << 3);
                f4 w = *(const f4*)(Wp + (size_t)i * 64 + q4p);
                double x = V[cls][i];
                a0 = fma(x, (double)w.x, a0);
                a1 = fma(x, (double)w.y, a1);
                a2 = fma(x, (double)w.z, a2);
                a3 = fma(x, (double)w.w, a3);
            }
            part[cls][hp][q4p+0] = a0; part[cls][hp][q4p+1] = a1;
            part[cls][hp][q4p+2] = a2; part[cls][hp][q4p+3] = a3;
        }
        __syncthreads();
        if (r < 64) {
            zp2[cls][r] = ((part[cls][0][r] + part[cls][1][r])
                         + (part[cls][2][r] + part[cls][3][r]))
                        + ((part[cls][4][r] + part[cls][5][r])
                         + (part[cls][6][r] + part[cls][7][r]));
        }
        __syncthreads();

        // VQ argmin: thread t owns codes t, t+256; each crow f4 load feeds
        // BOTH classes' distance chains (R7's s0/s1 even/odd order).
        double bestA = 1e300, bestB = 1e300; int biA = 0, biB = 0;
        for (int k = t; k < VQN; k += 256) {
            const float* crow = cb + (size_t)k * 64;
            double sA0 = 0.0, sA1 = 0.0, sB0 = 0.0, sB1 = 0.0;
            #pragma unroll
            for (int j = 0; j < 64; j += 4) {
                f4 v = *(const f4*)(crow + j);
                double w0 = (double)v.x, w1 = (double)v.y;
                double w2 = (double)v.z, w3 = (double)v.w;
                double dA0 = zp2[0][j+0] - w0, dA1 = zp2[0][j+1] - w1;
                double dA2 = zp2[0][j+2] - w2, dA3 = zp2[0][j+3] - w3;
                double dB0 = zp2[1][j+0] - w0, dB1 = zp2[1][j+1] - w1;
                double dB2 = zp2[1][j+2] - w2, dB3 = zp2[1][j+3] - w3;
                sA0 = fma(dA0, dA0, sA0);  sA1 = fma(dA1, dA1, sA1);
                sA0 = fma(dA2, dA2, sA0);  sA1 = fma(dA3, dA3, sA1);
                sB0 = fma(dB0, dB0, sB0);  sB1 = fma(dB1, dB1, sB1);
                sB0 = fma(dB2, dB2, sB0);  sB1 = fma(dB3, dB3, sB1);
            }
            double sA = sA0 + sA1, sB = sB0 + sB1;
            if (sA < bestA) { bestA = sA; biA = k; }   // first-min, ascending
            if (sB < bestB) { bestB = sB; biB = k; }
        }
        // (min d, min idx) lattice within wave, then across 4 waves via LDS
        for (int off = 32; off > 0; off >>= 1) {
            double od = __shfl_down(bestA, off);
            int    oi = __shfl_down(biA, off);
            if (od < bestA || (od == bestA && oi < biA)) { bestA = od; biA = oi; }
            od = __shfl_down(bestB, off);
            oi = __shfl_down(biB, off);
            if (od < bestB || (od == bestB && oi < biB)) { bestB = od; biB = oi; }
        }
        {
            int wv = t >> 6;
            if ((t & 63) == 0) {
                rda[0][wv] = bestA; ria[0][wv] = biA;
                rda[1][wv] = bestB; ria[1][wv] = biB;
            }
        }
        __syncthreads();
        if (t < 2) {
            double b0 = rda[t][0]; int i0 = ria[t][0];
            for (int wv = 1; wv < 4; ++wv) {
                if (rda[t][wv] < b0 || (rda[t][wv] == b0 && ria[t][wv] < i0)) {
                    b0 = rda[t][wv]; i0 = ria[t][wv];
                }
            }
            widx2[t] = i0;
        }
        __syncthreads();
        const int widxA = widx2[0], widxB = widx2[1];
        if (t < 64)       qv2[0][t]      = cb[(size_t)widxA * 64 + t];
        else if (t < 128) qv2[1][t - 64] = cb[(size_t)widxB * 64 + (t - 64)];
        __syncthreads();

        if (t == 0) {
            idx_t[c0] = widxA;
            double e0 = 0.0, e1 = 0.0;
            for (int j = 0; j < 64; j += 2) {
                double d0 = (double)qv2[0][j]   - zp2[0][j];
                double d1 = (double)qv2[0][j+1] - zp2[0][j+1];
                e0 = fma(d0, d0, e0); e1 = fma(d1, d1, e1);
            }
            e_t[c0] = (float)(e0 + e1);
        }
        if (t == 128 && c1 != c0) {
            idx_t[c1] = widxB;
            double e0 = 0.0, e1 = 0.0;
            for (int j = 0; j < 64; j += 2) {
                double d0 = (double)qv2[1][j]   - zp2[1][j];
                double d1 = (double)qv2[1][j+1] - zp2[1][j+1];
                e0 = fma(d0, d0, e0); e1 = fma(d1, d1, e1);
            }
            e_t[c1] = (float)(e0 + e1);
        }
    } else {
        // ============ heads per CODE (2 codes/block, R7-verbatim) ============
        const int g  = t >> 7;                 // code slot 0/1
        const int tt = t & 127;
        int k = (bid - nTB) * 2 + g;
        const int kk = (k < VQN) ? k : VQN - 1;    // clamp (dup-safe)
        const int q4 = (tt & 31) << 2;

        if (tt < 64) qvh[g][tt] = cb[(size_t)kk * 64 + tt];
        __syncthreads();

        // H1: slots (tt>>5): 0=Wa-even, 1=Wa-odd, 2=Ws-even, 3=Ws-odd
        {
            const int m  = tt >> 6;
            const int hh = (tt >> 5) & 1;
            const float* Wm = m ? Ws : Wa;
            const float* bm = m ? bs : ba;
            float a0 = hh ? 0.0f : bm[q4+0];
            float a1 = hh ? 0.0f : bm[q4+1];
            float a2 = hh ? 0.0f : bm[q4+2];
            float a3 = hh ? 0.0f : bm[q4+3];
            #pragma unroll
            for (int s = 0; s < 32; ++s) {
                int j = hh + (s << 1);
                f4 w = *(const f4*)(Wm + (size_t)j * 128 + q4);
                float qj = qvh[g][j];
                a0 = fmaf(qj, w.x, a0);
                a1 = fmaf(qj, w.y, a1);
                a2 = fmaf(qj, w.z, a2);
                a3 = fmaf(qj, w.w, a3);
            }
            fpart[g][tt >> 5][q4+0] = a0; fpart[g][tt >> 5][q4+1] = a1;
            fpart[g][tt >> 5][q4+2] = a2; fpart[g][tt >> 5][q4+3] = a3;
        }
        __syncthreads();

        // H2: tt<64 compute Wc1 chains; tt>=64 combine+store am/sd per code
        if (tt < 64) {
            const int hh = tt >> 5;
            float a0 = hh ? 0.0f : bc1[q4+0];
            float a1 = hh ? 0.0f : bc1[q4+1];
            float a2 = hh ? 0.0f : bc1[q4+2];
            float a3 = hh ? 0.0f : bc1[q4+3];
            #pragma unroll
            for (int s = 0; s < 32; ++s) {
                int j = hh + (s << 1);
                f4 w = *(const f4*)(Wc1 + (size_t)j * 128 + q4);
                float qj = qvh[g][j];
                a0 = fmaf(qj, w.x, a0);
                a1 = fmaf(qj, w.y, a1);
                a2 = fmaf(qj, w.z, a2);
                a3 = fmaf(qj, w.w, a3);
            }
            gpart[g][hh][q4+0] = a0; gpart[g][hh][q4+1] = a1;
            gpart[g][hh][q4+2] = a2; gpart[g][hh][q4+3] = a3;
        } else {
            int o = (tt - 64) << 1;
            am_c[(size_t)kk * 128 + o]     = sigmoidf_(fpart[g][0][o]   + fpart[g][1][o]);
            am_c[(size_t)kk * 128 + o + 1] = sigmoidf_(fpart[g][0][o+1] + fpart[g][1][o+1]);
            sd_c[(size_t)kk * 128 + o]     = sigmoidf_(fpart[g][2][o]   + fpart[g][3][o])   * 1.0f + 1e-8f;
            sd_c[(size_t)kk * 128 + o + 1] = sigmoidf_(fpart[g][2][o+1] + fpart[g][3][o+1]) * 1.0f + 1e-8f;
        }
        __syncthreads();
        h1s[g][tt] = sigmoidf_(gpart[g][0][tt] + gpart[g][1][tt]);
        __syncthreads();

        // critic layer 2 (128->128): 64 o-pairs x 2 chains, f2 loads
        {
            const int o2 = (tt & 63) << 1;
            const int hh = tt >> 6;
            float a0 = hh ? 0.0f : bc2[o2+0];
            float a1 = hh ? 0.0f : bc2[o2+1];
            #pragma unroll
            for (int s = 0; s < 64; ++s) {
                int i = hh + (s << 1);
                f2 w = *(const f2*)(Wc2 + (size_t)i * 128 + o2);
                float x = h1s[g][i];
                a0 = fmaf(x, w.x, a0);
                a1 = fmaf(x, w.y, a1);
            }
            gpart[g][hh][o2+0] = a0; gpart[g][hh][o2+1] = a1;
        }
        __syncthreads();
        h2s[g][tt] = sigmoidf_(gpart[g][0][tt] + gpart[g][1][tt]);
        __syncthreads();

        // critic layer 3 (128->32): 16 o-pairs x 2 chains, f2 loads
        if (tt < 32) {
            const int o2 = (tt & 15) << 1;
            const int hh = tt >> 4;
            float a0 = hh ? 0.0f : bc3[o2+0];
            float a1 = hh ? 0.0f : bc3[o2+1];
            #pragma unroll
            for (int s = 0; s < 64; ++s) {
                int i = hh + (s << 1);
                f2 w = *(const f2*)(Wc3 + (size_t)i * 32 + o2);
                float x = h2s[g][i];
                a0 = fmaf(x, w.x, a0);
                a1 = fmaf(x, w.y, a1);
            }
            gpart[g][hh][o2+0] = a0; gpart[g][hh][o2+1] = a1;
        }
        __syncthreads();
        if (tt < 32) h3s[g][tt] = sigmoidf_(gpart[g][0][tt] + gpart[g][1][tt]);
        __syncthreads();

        if (tt == 0) {
            float l4 = bc4[0];
            for (int i = 0; i < 32; ++i) l4 = fmaf(h3s[g][i], Wc4[i], l4);
            cr_c[kk] = l4;             // no sigmoid on final critic layer
        }
    }
}

// Merged scatter: blocks [0, vecBlocks) emit BOTH am and sd float4 per
// thread from one obs read + one idx_t indirection (L1-hot, 4 KB);
// trailing blocks do the critic/idx scatter and vq_loss reduction.
__global__ __launch_bounds__(256) void scatter_kernel(
    const int* __restrict__ obs,
    const f4* __restrict__ am_c, const f4* __restrict__ sd_c,
    const float* __restrict__ cr_c, const int* __restrict__ idx_t,
    const float* __restrict__ e_t,
    f4* __restrict__ out_vec, float* __restrict__ out_critic,
    float* __restrict__ out_idx, float* __restrict__ out_loss,
    int B, float scale)
{
    __shared__ float red[256];
    const int vecBlocks = (B * 32) / 256;           // B*128/4 f4-slots per half
    if ((int)blockIdx.x < vecBlocks) {
        int gid = blockIdx.x * 256 + threadIdx.x;
        int b = gid >> 5;                           // 32 float4 per row
        int j = gid & 31;
        int k = idx_t[obs[b]];
        size_t row = (size_t)k * 32 + j;
        __builtin_nontemporal_store(am_c[row], &out_vec[gid]);
        __builtin_nontemporal_store(sd_c[row], &out_vec[(size_t)B * 32 + gid]);
        return;
    }
    int b = (blockIdx.x - vecBlocks) * 256 + threadIdx.x;
    float e = 0.0f;
    if (b < B) {
        int o = obs[b];
        int k = idx_t[o];
        __builtin_nontemporal_store(cr_c[k], &out_critic[b]);
        __builtin_nontemporal_store((float)k, &out_idx[b]);
        e = e_t[o];
    }
    red[threadIdx.x] = e;
    __syncthreads();
    for (int s = 128; s > 0; s >>= 1) {
        if (threadIdx.x < s) red[threadIdx.x] += red[threadIdx.x + s];
        __syncthreads();
    }
    if (threadIdx.x == 0) atomicAdd(out_loss, red[0] * scale);
}

extern "C" void kernel_launch(void* const* d_in, const int* in_sizes, int n_in,
                              void* d_out, int out_size, void* d_ws, size_t ws_size,
                              hipStream_t stream)
{
    const int*   obs   = (const int*)  d_in[0];
    const float* embed = (const float*)d_in[1];
    const float* W1    = (const float*)d_in[2];
    const float* b1    = (const float*)d_in[3];
    const float* W2    = (const float*)d_in[4];
    const float* b2    = (const float*)d_in[5];
    const float* W3    = (const float*)d_in[6];
    const float* b3    = (const float*)d_in[7];
    const float* Wp    = (const float*)d_in[8];
    const float* bp    = (const float*)d_in[9];
    const float* cb    = (const float*)d_in[10];
    const float* Wa    = (const float*)d_in[11];
    const float* ba    = (const float*)d_in[12];
    const float* Ws    = (const float*)d_in[13];
    const float* bs    = (const float*)d_in[14];
    const float* Wc1   = (const float*)d_in[15];
    const float* bc1   = (const float*)d_in[16];
    const float* Wc2   = (const float*)d_in[17];
    const float* bc2   = (const float*)d_in[18];
    const float* Wc3   = (const float*)d_in[19];
    const float* bc3   = (const float*)d_in[20];
    const float* Wc4   = (const float*)d_in[21];
    const float* bc4   = (const float*)d_in[22];

    const int B   = in_sizes[0];
    const int NC  = in_sizes[1] / 128;
    const int VQN = in_sizes[10] / 64;

    // workspace tables: per-code am/sd/cr + per-class idx/e (~530 KB)
    float* am_c = (float*)d_ws;
    float* sd_c = am_c + (size_t)VQN * 128;
    float* cr_c = sd_c + (size_t)VQN * 128;
    float* e_t  = cr_c + VQN;
    int*   idx_t = (int*)(e_t + NC);

    float* out = (float*)d_out;
    const size_t cr_off   = (size_t)B * 256;     // after am (B*128) + sd (B*128)
    const size_t loss_off = cr_off + (size_t)B;
    const size_t idx_off  = loss_off + 1;

    const int nTB = (NC + 1) / 2;                // trunk blocks (2 classes each)
    const int nHB = (VQN + 1) / 2;               // head blocks (2 codes each)

    compute_kernel<<<nTB + nHB, 256, 0, stream>>>(
        embed, W1, b1, W2, b2, W3, b3, Wp, bp, cb,
        Wa, ba, Ws, bs, Wc1, bc1, Wc2, bc2, Wc3, bc3, Wc4, bc4,
        am_c, sd_c, cr_c, idx_t, e_t, out + loss_off, VQN, NC, nTB);

    const int vecBlocks    = (B * 32) / 256;
    const int scalarBlocks = (B + 255) / 256;
    scatter_kernel<<<vecBlocks + scalarBlocks, 256, 0, stream>>>(
        obs, (const f4*)am_c, (const f4*)sd_c, cr_c, idx_t, e_t,
        (f4*)out, out + cr_off, out + idx_off, out + loss_off,
        B, 1.25f / ((float)B * 64.0f));
}

// Round 6
// 234.422 us; speedup vs baseline: 1.6137x; 1.0203x over previous
//
#include <hip/hip_runtime.h>
#include <math.h>

// Outputs are a pure function of obs's class (NC=1000); heads (am/sd/cr)
// are a pure function of the VQ CODE (VQN=512). Structure as R8:
//   compute kernel: blocks [0,nTB) trunk+VQ (2 classes, shared f4 loads);
//                   blocks [nTB,+nHB) heads per code (2 codes/block).
//   scatter: out[b] = tables[idx_t[obs[b]]].
//
// R9: R5's counters (VALUBusy 5.9% -> ~94% stall, ~500cy PER LOAD) showed
// the inner loops serialize every global load behind per-iteration waits
// (mixed LDS+VMEM streams). Fix: batch-issue each phase's global loads
// into a fully-unrolled register array FIRST (one pipelined vmcnt wait),
// then FMA with LDS reads inline (lgkmcnt independent). Accumulation
// order per chain is unchanged => bit-identical outputs, absmax 0.

typedef float f4 __attribute__((ext_vector_type(4)));
typedef float f2 __attribute__((ext_vector_type(2)));

__device__ __forceinline__ float sigmoidf_(float x){ return 1.0f/(1.0f + expf(-x)); }

__global__ __launch_bounds__(256) void compute_kernel(
    const float* __restrict__ embed,
    const float* __restrict__ W1, const float* __restrict__ b1,
    const float* __restrict__ W2, const float* __restrict__ b2,
    const float* __restrict__ W3, const float* __restrict__ b3,
    const float* __restrict__ Wp, const float* __restrict__ bp,
    const float* __restrict__ cb,
    const float* __restrict__ Wa, const float* __restrict__ ba,
    const float* __restrict__ Ws, const float* __restrict__ bs,
    const float* __restrict__ Wc1, const float* __restrict__ bc1,
    const float* __restrict__ Wc2, const float* __restrict__ bc2,
    const float* __restrict__ Wc3, const float* __restrict__ bc3,
    const float* __restrict__ Wc4, const float* __restrict__ bc4,
    float* __restrict__ am_c, float* __restrict__ sd_c,
    float* __restrict__ cr_c, int* __restrict__ idx_t, float* __restrict__ e_t,
    float* __restrict__ loss_slot, int VQN, int NC, int nTB)
{
    const int bid = blockIdx.x;
    const int t   = threadIdx.x;     // 0..255
    if (bid == 0 && t == 0) *loss_slot = 0.0f;   // d_out is poisoned each call

    // trunk-branch LDS
    __shared__ double U[2][128], V[2][128];     // layer ping-pong (class A/B)
    __shared__ double part[2][8][128];          // fp64 chain partials
    __shared__ double zp2[2][64];
    __shared__ float  qv2[2][64];
    __shared__ double rda[2][4];
    __shared__ int    ria[2][4];
    __shared__ int    widx2[2];
    // head-branch LDS
    __shared__ float  qvh[2][64];
    __shared__ float  fpart[2][4][128];
    __shared__ float  gpart[2][2][128];
    __shared__ float  h1s[2][128], h2s[2][128], h3s[2][32];

    if (bid < nTB) {
        // ================= trunk + VQ for classes c0, c1 =================
        const int c0  = bid * 2;
        const int c1  = (c0 + 1 < NC) ? c0 + 1 : NC - 1;   // clamp (dup-safe)
        const int cls = t >> 7;          // this thread's class for combines
        const int r   = t & 127;
        const int q4  = (t & 31) << 2;   // output quad (shared-load phases)
        const int h   = t >> 5;          // K-chain 0..7 (i ≡ h mod 8)

        if (t < 128) U[0][t] = (double)embed[(size_t)c0 * 128 + t];
        else         U[1][r] = (double)embed[(size_t)c1 * 128 + r];
        __syncthreads();

        // trunk layer: batch-issue 16 f4 weight loads into regs (single
        // pipelined vmcnt wait), then FMA with LDS inputs inline. Chain 0
        // carries the bias. Per-chain accumulation order == R8.
#define TRUNK2(Wm, bv, IN, OUT)                                               \
        {                                                                     \
            f4 w[16];                                                         \
            _Pragma("unroll")                                                 \
            for (int s = 0; s < 16; ++s)                                      \
                w[s] = *(const f4*)(Wm + (size_t)(h + (s << 3)) * 128 + q4);  \
            f4 bb = *(const f4*)(bv + q4);                                    \
            double aA0 = (h == 0) ? (double)bb.x : 0.0;                       \
            double aA1 = (h == 0) ? (double)bb.y : 0.0;                       \
            double aA2 = (h == 0) ? (double)bb.z : 0.0;                       \
            double aA3 = (h == 0) ? (double)bb.w : 0.0;                       \
            double aB0 = aA0, aB1 = aA1, aB2 = aA2, aB3 = aA3;                \
            _Pragma("unroll")                                                 \
            for (int s = 0; s < 16; ++s) {                                    \
                int i = h + (s << 3);                                         \
                double w0 = (double)w[s].x, w1 = (double)w[s].y;              \
                double w2 = (double)w[s].z, w3 = (double)w[s].w;              \
                double xA = IN[0][i], xB = IN[1][i];                          \
                aA0 = fma(xA, w0, aA0);  aB0 = fma(xB, w0, aB0);              \
                aA1 = fma(xA, w1, aA1);  aB1 = fma(xB, w1, aB1);              \
                aA2 = fma(xA, w2, aA2);  aB2 = fma(xB, w2, aB2);              \
                aA3 = fma(xA, w3, aA3);  aB3 = fma(xB, w3, aB3);              \
            }                                                                 \
            part[0][h][q4+0] = aA0; part[0][h][q4+1] = aA1;                   \
            part[0][h][q4+2] = aA2; part[0][h][q4+3] = aA3;                   \
            part[1][h][q4+0] = aB0; part[1][h][q4+1] = aB1;                   \
            part[1][h][q4+2] = aB2; part[1][h][q4+3] = aB3;                   \
        }                                                                     \
        __syncthreads();                                                      \
        {                                                                     \
            double acc = ((part[cls][0][r] + part[cls][1][r])                 \
                        + (part[cls][2][r] + part[cls][3][r]))                \
                       + ((part[cls][4][r] + part[cls][5][r])                 \
                        + (part[cls][6][r] + part[cls][7][r]));               \
            OUT[cls][r] = acc > 0.0 ? acc : 0.0;                              \
        }                                                                     \
        __syncthreads();

        TRUNK2(W1, b1, U, V)
        TRUNK2(W2, b2, V, U)
        TRUNK2(W3, b3, U, V)
#undef TRUNK2

        // zp = z3 @ Wp + bp (64 outs/class): 8 chains x 16 quads, batched
        {
            const int q4p = (r & 15) << 2;
            const int hp  = r >> 4;          // 0..7
            f4 w[16];
            #pragma unroll
            for (int s = 0; s < 16; ++s)
                w[s] = *(const f4*)(Wp + (size_t)(hp + (s << 3)) * 64 + q4p);
            f4 bb = *(const f4*)(bp + q4p);
            double a0 = (hp == 0) ? (double)bb.x : 0.0;
            double a1 = (hp == 0) ? (double)bb.y : 0.0;
            double a2 = (hp == 0) ? (double)bb.z : 0.0;
            double a3 = (hp == 0) ? (double)bb.w : 0.0;
            #pragma unroll
            for (int s = 0; s < 16; ++s) {
                int i = hp + (s << 3);
                double x = V[cls][i];
                a0 = fma(x, (double)w[s].x, a0);
                a1 = fma(x, (double)w[s].y, a1);
                a2 = fma(x, (double)w[s].z, a2);
                a3 = fma(x, (double)w[s].w, a3);
            }
            part[cls][hp][q4p+0] = a0; part[cls][hp][q4p+1] = a1;
            part[cls][hp][q4p+2] = a2; part[cls][hp][q4p+3] = a3;
        }
        __syncthreads();
        if (r < 64) {
            zp2[cls][r] = ((part[cls][0][r] + part[cls][1][r])
                         + (part[cls][2][r] + part[cls][3][r]))
                        + ((part[cls][4][r] + part[cls][5][r])
                         + (part[cls][6][r] + part[cls][7][r]));
        }
        __syncthreads();

        // VQ argmin: thread t owns codes t, t+256; batch each code's 16
        // row-f4s into regs, then distance chains (R8's exact order).
        double bestA = 1e300, bestB = 1e300; int biA = 0, biB = 0;
        for (int k = t; k < VQN; k += 256) {
            const float* crow = cb + (size_t)k * 64;
            f4 v[16];
            #pragma unroll
            for (int j4 = 0; j4 < 16; ++j4)
                v[j4] = *(const f4*)(crow + (j4 << 2));
            double sA0 = 0.0, sA1 = 0.0, sB0 = 0.0, sB1 = 0.0;
            #pragma unroll
            for (int j4 = 0; j4 < 16; ++j4) {
                int j = j4 << 2;
                double w0 = (double)v[j4].x, w1 = (double)v[j4].y;
                double w2 = (double)v[j4].z, w3 = (double)v[j4].w;
                double dA0 = zp2[0][j+0] - w0, dA1 = zp2[0][j+1] - w1;
                double dA2 = zp2[0][j+2] - w2, dA3 = zp2[0][j+3] - w3;
                double dB0 = zp2[1][j+0] - w0, dB1 = zp2[1][j+1] - w1;
                double dB2 = zp2[1][j+2] - w2, dB3 = zp2[1][j+3] - w3;
                sA0 = fma(dA0, dA0, sA0);  sA1 = fma(dA1, dA1, sA1);
                sA0 = fma(dA2, dA2, sA0);  sA1 = fma(dA3, dA3, sA1);
                sB0 = fma(dB0, dB0, sB0);  sB1 = fma(dB1, dB1, sB1);
                sB0 = fma(dB2, dB2, sB0);  sB1 = fma(dB3, dB3, sB1);
            }
            double sA = sA0 + sA1, sB = sB0 + sB1;
            if (sA < bestA) { bestA = sA; biA = k; }   // first-min, ascending
            if (sB < bestB) { bestB = sB; biB = k; }
        }
        // (min d, min idx) lattice within wave, then across 4 waves via LDS
        for (int off = 32; off > 0; off >>= 1) {
            double od = __shfl_down(bestA, off);
            int    oi = __shfl_down(biA, off);
            if (od < bestA || (od == bestA && oi < biA)) { bestA = od; biA = oi; }
            od = __shfl_down(bestB, off);
            oi = __shfl_down(biB, off);
            if (od < bestB || (od == bestB && oi < biB)) { bestB = od; biB = oi; }
        }
        {
            int wv = t >> 6;
            if ((t & 63) == 0) {
                rda[0][wv] = bestA; ria[0][wv] = biA;
                rda[1][wv] = bestB; ria[1][wv] = biB;
            }
        }
        __syncthreads();
        if (t < 2) {
            double b0 = rda[t][0]; int i0 = ria[t][0];
            for (int wv = 1; wv < 4; ++wv) {
                if (rda[t][wv] < b0 || (rda[t][wv] == b0 && ria[t][wv] < i0)) {
                    b0 = rda[t][wv]; i0 = ria[t][wv];
                }
            }
            widx2[t] = i0;
        }
        __syncthreads();
        const int widxA = widx2[0], widxB = widx2[1];
        if (t < 64)       qv2[0][t]      = cb[(size_t)widxA * 64 + t];
        else if (t < 128) qv2[1][t - 64] = cb[(size_t)widxB * 64 + (t - 64)];
        __syncthreads();

        if (t == 0) {
            idx_t[c0] = widxA;
            double e0 = 0.0, e1 = 0.0;
            for (int j = 0; j < 64; j += 2) {
                double d0 = (double)qv2[0][j]   - zp2[0][j];
                double d1 = (double)qv2[0][j+1] - zp2[0][j+1];
                e0 = fma(d0, d0, e0); e1 = fma(d1, d1, e1);
            }
            e_t[c0] = (float)(e0 + e1);
        }
        if (t == 128 && c1 != c0) {
            idx_t[c1] = widxB;
            double e0 = 0.0, e1 = 0.0;
            for (int j = 0; j < 64; j += 2) {
                double d0 = (double)qv2[1][j]   - zp2[1][j];
                double d1 = (double)qv2[1][j+1] - zp2[1][j+1];
                e0 = fma(d0, d0, e0); e1 = fma(d1, d1, e1);
            }
            e_t[c1] = (float)(e0 + e1);
        }
    } else {
        // ============ heads per CODE (2 codes/block, batched loads) ============
        const int g  = t >> 7;                 // code slot 0/1
        const int tt = t & 127;
        int k = (bid - nTB) * 2 + g;
        const int kk = (k < VQN) ? k : VQN - 1;    // clamp (dup-safe)
        const int q4 = (tt & 31) << 2;

        if (tt < 64) qvh[g][tt] = cb[(size_t)kk * 64 + tt];
        __syncthreads();

        // H1: slots (tt>>5): 0=Wa-even, 1=Wa-odd, 2=Ws-even, 3=Ws-odd.
        // 32 f4 loads as two batched groups of 16; chain order == R8.
        {
            const int m  = tt >> 6;
            const int hh = (tt >> 5) & 1;
            const float* Wm = m ? Ws : Wa;
            const float* bm = m ? bs : ba;
            f4 bb = *(const f4*)(bm + q4);
            float a0 = hh ? 0.0f : bb.x;
            float a1 = hh ? 0.0f : bb.y;
            float a2 = hh ? 0.0f : bb.z;
            float a3 = hh ? 0.0f : bb.w;
            f4 w[16];
            #pragma unroll
            for (int s = 0; s < 16; ++s)
                w[s] = *(const f4*)(Wm + (size_t)(hh + (s << 1)) * 128 + q4);
            #pragma unroll
            for (int s = 0; s < 16; ++s) {
                float qj = qvh[g][hh + (s << 1)];
                a0 = fmaf(qj, w[s].x, a0);
                a1 = fmaf(qj, w[s].y, a1);
                a2 = fmaf(qj, w[s].z, a2);
                a3 = fmaf(qj, w[s].w, a3);
            }
            #pragma unroll
            for (int s = 0; s < 16; ++s)
                w[s] = *(const f4*)(Wm + (size_t)(hh + ((s + 16) << 1)) * 128 + q4);
            #pragma unroll
            for (int s = 0; s < 16; ++s) {
                float qj = qvh[g][hh + ((s + 16) << 1)];
                a0 = fmaf(qj, w[s].x, a0);
                a1 = fmaf(qj, w[s].y, a1);
                a2 = fmaf(qj, w[s].z, a2);
                a3 = fmaf(qj, w[s].w, a3);
            }
            fpart[g][tt >> 5][q4+0] = a0; fpart[g][tt >> 5][q4+1] = a1;
            fpart[g][tt >> 5][q4+2] = a2; fpart[g][tt >> 5][q4+3] = a3;
        }
        __syncthreads();

        // H2: tt<64 compute Wc1 chains (batched); tt>=64 combine+store am/sd
        if (tt < 64) {
            const int hh = tt >> 5;
            f4 bb = *(const f4*)(bc1 + q4);
            float a0 = hh ? 0.0f : bb.x;
            float a1 = hh ? 0.0f : bb.y;
            float a2 = hh ? 0.0f : bb.z;
            float a3 = hh ? 0.0f : bb.w;
            f4 w[16];
            #pragma unroll
            for (int s = 0; s < 16; ++s)
                w[s] = *(const f4*)(Wc1 + (size_t)(hh + (s << 1)) * 128 + q4);
            #pragma unroll
            for (int s = 0; s < 16; ++s) {
                float qj = qvh[g][hh + (s << 1)];
                a0 = fmaf(qj, w[s].x, a0);
                a1 = fmaf(qj, w[s].y, a1);
                a2 = fmaf(qj, w[s].z, a2);
                a3 = fmaf(qj, w[s].w, a3);
            }
            #pragma unroll
            for (int s = 0; s < 16; ++s)
                w[s] = *(const f4*)(Wc1 + (size_t)(hh + ((s + 16) << 1)) * 128 + q4);
            #pragma unroll
            for (int s = 0; s < 16; ++s) {
                float qj = qvh[g][hh + ((s + 16) << 1)];
                a0 = fmaf(qj, w[s].x, a0);
                a1 = fmaf(qj, w[s].y, a1);
                a2 = fmaf(qj, w[s].z, a2);
                a3 = fmaf(qj, w[s].w, a3);
            }
            gpart[g][hh][q4+0] = a0; gpart[g][hh][q4+1] = a1;
            gpart[g][hh][q4+2] = a2; gpart[g][hh][q4+3] = a3;
        } else {
            int o = (tt - 64) << 1;
            am_c[(size_t)kk * 128 + o]     = sigmoidf_(fpart[g][0][o]   + fpart[g][1][o]);
            am_c[(size_t)kk * 128 + o + 1] = sigmoidf_(fpart[g][0][o+1] + fpart[g][1][o+1]);
            sd_c[(size_t)kk * 128 + o]     = sigmoidf_(fpart[g][2][o]   + fpart[g][3][o])   * 1.0f + 1e-8f;
            sd_c[(size_t)kk * 128 + o + 1] = sigmoidf_(fpart[g][2][o+1] + fpart[g][3][o+1]) * 1.0f + 1e-8f;
        }
        __syncthreads();
        h1s[g][tt] = sigmoidf_(gpart[g][0][tt] + gpart[g][1][tt]);
        __syncthreads();

        // critic layer 2 (128->128): 64 iters as 4 batched groups of 16 f2
        {
            const int o2 = (tt & 63) << 1;
            const int hh = tt >> 6;
            f2 bb = *(const f2*)(bc2 + o2);
            float a0 = hh ? 0.0f : bb.x;
            float a1 = hh ? 0.0f : bb.y;
            #pragma unroll
            for (int gq = 0; gq < 4; ++gq) {
                f2 w[16];
                #pragma unroll
                for (int s = 0; s < 16; ++s) {
                    int i = hh + (((gq << 4) + s) << 1);
                    w[s] = *(const f2*)(Wc2 + (size_t)i * 128 + o2);
                }
                #pragma unroll
                for (int s = 0; s < 16; ++s) {
                    int i = hh + (((gq << 4) + s) << 1);
                    float x = h1s[g][i];
                    a0 = fmaf(x, w[s].x, a0);
                    a1 = fmaf(x, w[s].y, a1);
                }
            }
            gpart[g][hh][o2+0] = a0; gpart[g][hh][o2+1] = a1;
        }
        __syncthreads();
        h2s[g][tt] = sigmoidf_(gpart[g][0][tt] + gpart[g][1][tt]);
        __syncthreads();

        // critic layer 3 (128->32): 4 batched groups of 16 f2, tt<32
        if (tt < 32) {
            const int o2 = (tt & 15) << 1;
            const int hh = tt >> 4;
            f2 bb = *(const f2*)(bc3 + o2);
            float a0 = hh ? 0.0f : bb.x;
            float a1 = hh ? 0.0f : bb.y;
            #pragma unroll
            for (int gq = 0; gq < 4; ++gq) {
                f2 w[16];
                #pragma unroll
                for (int s = 0; s < 16; ++s) {
                    int i = hh + (((gq << 4) + s) << 1);
                    w[s] = *(const f2*)(Wc3 + (size_t)i * 32 + o2);
                }
                #pragma unroll
                for (int s = 0; s < 16; ++s) {
                    int i = hh + (((gq << 4) + s) << 1);
                    float x = h2s[g][i];
                    a0 = fmaf(x, w[s].x, a0);
                    a1 = fmaf(x, w[s].y, a1);
                }
            }
            gpart[g][hh][o2+0] = a0; gpart[g][hh][o2+1] = a1;
        }
        __syncthreads();
        if (tt < 32) h3s[g][tt] = sigmoidf_(gpart[g][0][tt] + gpart[g][1][tt]);
        __syncthreads();

        if (tt == 0) {
            float l4 = bc4[0];
            for (int i = 0; i < 32; ++i) l4 = fmaf(h3s[g][i], Wc4[i], l4);
            cr_c[kk] = l4;             // no sigmoid on final critic layer
        }
    }
}

// Merged scatter: blocks [0, vecBlocks) emit BOTH am and sd float4 per
// thread from one obs read + one idx_t indirection (L1-hot, 4 KB);
// trailing blocks do the critic/idx scatter and vq_loss reduction.
__global__ __launch_bounds__(256) void scatter_kernel(
    const int* __restrict__ obs,
    const f4* __restrict__ am_c, const f4* __restrict__ sd_c,
    const float* __restrict__ cr_c, const int* __restrict__ idx_t,
    const float* __restrict__ e_t,
    f4* __restrict__ out_vec, float* __restrict__ out_critic,
    float* __restrict__ out_idx, float* __restrict__ out_loss,
    int B, float scale)
{
    __shared__ float red[256];
    const int vecBlocks = (B * 32) / 256;           // B*128/4 f4-slots per half
    if ((int)blockIdx.x < vecBlocks) {
        int gid = blockIdx.x * 256 + threadIdx.x;
        int b = gid >> 5;                           // 32 float4 per row
        int j = gid & 31;
        int k = idx_t[obs[b]];
        size_t row = (size_t)k * 32 + j;
        __builtin_nontemporal_store(am_c[row], &out_vec[gid]);
        __builtin_nontemporal_store(sd_c[row], &out_vec[(size_t)B * 32 + gid]);
        return;
    }
    int b = (blockIdx.x - vecBlocks) * 256 + threadIdx.x;
    float e = 0.0f;
    if (b < B) {
        int o = obs[b];
        int k = idx_t[o];
        __builtin_nontemporal_store(cr_c[k], &out_critic[b]);
        __builtin_nontemporal_store((float)k, &out_idx[b]);
        e = e_t[o];
    }
    red[threadIdx.x] = e;
    __syncthreads();
    for (int s = 128; s > 0; s >>= 1) {
        if (threadIdx.x < s) red[threadIdx.x] += red[threadIdx.x + s];
        __syncthreads();
    }
    if (threadIdx.x == 0) atomicAdd(out_loss, red[0] * scale);
}

extern "C" void kernel_launch(void* const* d_in, const int* in_sizes, int n_in,
                              void* d_out, int out_size, void* d_ws, size_t ws_size,
                              hipStream_t stream)
{
    const int*   obs   = (const int*)  d_in[0];
    const float* embed = (const float*)d_in[1];
    const float* W1    = (const float*)d_in[2];
    const float* b1    = (const float*)d_in[3];
    const float* W2    = (const float*)d_in[4];
    const float* b2    = (const float*)d_in[5];
    const float* W3    = (const float*)d_in[6];
    const float* b3    = (const float*)d_in[7];
    const float* Wp    = (const float*)d_in[8];
    const float* bp    = (const float*)d_in[9];
    const float* cb    = (const float*)d_in[10];
    const float* Wa    = (const float*)d_in[11];
    const float* ba    = (const float*)d_in[12];
    const float* Ws    = (const float*)d_in[13];
    const float* bs    = (const float*)d_in[14];
    const float* Wc1   = (const float*)d_in[15];
    const float* bc1   = (const float*)d_in[16];
    const float* Wc2   = (const float*)d_in[17];
    const float* bc2   = (const float*)d_in[18];
    const float* Wc3   = (const float*)d_in[19];
    const float* bc3   = (const float*)d_in[20];
    const float* Wc4   = (const float*)d_in[21];
    const float* bc4   = (const float*)d_in[22];

    const int B   = in_sizes[0];
    const int NC  = in_sizes[1] / 128;
    const int VQN = in_sizes[10] / 64;

    // workspace tables: per-code am/sd/cr + per-class idx/e (~530 KB)
    float* am_c = (float*)d_ws;
    float* sd_c = am_c + (size_t)VQN * 128;
    float* cr_c = sd_c + (size_t)VQN * 128;
    float* e_t  = cr_c + VQN;
    int*   idx_t = (int*)(e_t + NC);

    float* out = (float*)d_out;
    const size_t cr_off   = (size_t)B * 256;     // after am (B*128) + sd (B*128)
    const size_t loss_off = cr_off + (size_t)B;
    const size_t idx_off  = loss_off + 1;

    const int nTB = (NC + 1) / 2;                // trunk blocks (2 classes each)
    const int nHB = (VQN + 1) / 2;               // head blocks (2 codes each)

    compute_kernel<<<nTB + nHB, 256, 0, stream>>>(
        embed, W1, b1, W2, b2, W3, b3, Wp, bp, cb,
        Wa, ba, Ws, bs, Wc1, bc1, Wc2, bc2, Wc3, bc3, Wc4, bc4,
        am_c, sd_c, cr_c, idx_t, e_t, out + loss_off, VQN, NC, nTB);

    const int vecBlocks    = (B * 32) / 256;
    const int scalarBlocks = (B + 255) / 256;
    scatter_kernel<<<vecBlocks + scalarBlocks, 256, 0, stream>>>(
        obs, (const f4*)am_c, (const f4*)sd_c, cr_c, idx_t, e_t,
        (f4*)out, out + cr_off, out + idx_off, out + loss_off,
        B, 1.25f / ((float)B * 64.0f));
}